// Round 17
// baseline (149.446 us; speedup 1.0000x reference)
//
#include <hip/hip_runtime.h>
#include <hip/hip_bf16.h>

typedef float f32x4 __attribute__((ext_vector_type(4)));
typedef short short8 __attribute__((ext_vector_type(8)));
typedef unsigned int u32;

#define LOG2E 1.44269504088896f

// ---------------- ws layout (float offsets) ----------------
#define WS_POOL 0
#define WS_G    1024
#define WS_QK   2048
#define WS_MK   133120
#define WS_VT   134144
#define WS_WT   1182720            // bf16 [tap][co][ci] 36864 elems
#define WS_WTV  1201152            // bf16 [64co][64ci]  4096 elems
#define WS_WQK  1203200            // bf16 [16][64ci]    1024 elems
#define WS_CTX  1219584            // bf16 [b][c][y][x] 2097152 elems
#define WS_PDEN 3316736            // f32 [1024 tiles][64]
#define WS_PNUM2 3382272           // f32 [1024 tiles][4096]
#define WS_SPLIT2_BYTES ((size_t)(WS_PNUM2 + 4194304) * 4)

// ---------------- 1. adaptive max pool 128x128 -> 2x2 (+ mk zero-init) ----
__global__ void k_pool(const float* __restrict__ x, float* __restrict__ pool,
                       u32* __restrict__ mk){
  if (blockIdx.x == 0 && threadIdx.x < 16) mk[threadIdx.x] = 0u;
  int bid = blockIdx.x;            // ((b*64+c)*4 + t)
  int t4 = bid & 3; int c = (bid >> 2) & 63; int b = bid >> 8;
  int i = t4 >> 1, j = t4 & 1;
  const float* base = x + (((b*64 + c)*128) + i*64)*128 + j*64;
  int tid = threadIdx.x;
  float m = -3.402823466e38f;
  for (int k = tid; k < 4096; k += 256){
    int r = k >> 6, cc = k & 63;
    m = fmaxf(m, base[r*128 + cc]);
  }
  __shared__ float red[256];
  red[tid] = m; __syncthreads();
  for (int s = 128; s > 0; s >>= 1){
    if (tid < s) red[tid] = fmaxf(red[tid], red[tid + s]);
    __syncthreads();
  }
  if (tid == 0) pool[bid] = red[0];
}

// ---------------- 2. tiny non-local on pooled 2x2  +  weight transforms ---
__global__ void k_gca_wt(const float* __restrict__ pool,
                      const float* qw, const float* qb,
                      const float* kw, const float* kb,
                      const float* vw, const float* vb,
                      const float* gamma, float* __restrict__ g,
                      const float* __restrict__ w, __hip_bfloat16* __restrict__ wtb,
                      __hip_bfloat16* __restrict__ wtv,
                      __hip_bfloat16* __restrict__ wqkb){
  if (blockIdx.x >= 2){
    int idx = (int)(blockIdx.x - 2)*256 + threadIdx.x;   // 41984 total
    if (idx < 36864){
      int ci = idx & 63; int t2 = idx >> 6; int co = t2 & 63; int tap = t2 >> 6;
      wtb[idx] = __float2bfloat16(w[(co*64 + ci)*9 + tap]);
    } else if (idx < 40960){
      int i2 = idx - 36864;
      wtv[i2] = __float2bfloat16(vw[i2]);
    } else if (idx < 41984){
      int i3 = idx - 40960; int row = i3 >> 6; int ci = i3 & 63;
      float v = 0.f;
      if (row == 0) v = qw[ci];
      else if (row == 1) v = qw[64 + ci];
      else if (row == 2) v = kw[ci];
      else if (row == 3) v = kw[64 + ci];
      wqkb[i3] = __float2bfloat16(v);
    }
    return;
  }
  int b = blockIdx.x; int c = threadIdx.x;
  __shared__ float P[64][4];
  if (c < 64){
    #pragma unroll
    for (int t = 0; t < 4; t++) P[c][t] = pool[(b*64 + c)*4 + t];
  }
  __syncthreads();
  if (c >= 64) return;
  float q[2][4], kk[2][4];
  #pragma unroll
  for (int i = 0; i < 2; i++)
    #pragma unroll
    for (int n = 0; n < 4; n++){
      float a = qb[i], e = kb[i];
      for (int ci = 0; ci < 64; ci++){
        a += qw[i*64 + ci] * P[ci][n];
        e += kw[i*64 + ci] * P[ci][n];
      }
      q[i][n] = a; kk[i][n] = e;
    }
  float att[4][4];
  #pragma unroll
  for (int n = 0; n < 4; n++){
    float mx = -3.402823466e38f;
    #pragma unroll
    for (int m2 = 0; m2 < 4; m2++){
      att[n][m2] = q[0][n]*kk[0][m2] + q[1][n]*kk[1][m2];
      mx = fmaxf(mx, att[n][m2]);
    }
    float s = 0.f;
    #pragma unroll
    for (int m2 = 0; m2 < 4; m2++){ att[n][m2] = __expf(att[n][m2] - mx); s += att[n][m2]; }
    float inv = 1.f / s;
    #pragma unroll
    for (int m2 = 0; m2 < 4; m2++) att[n][m2] *= inv;
  }
  float v[4];
  #pragma unroll
  for (int m2 = 0; m2 < 4; m2++){
    float a = vb[c];
    for (int ci = 0; ci < 64; ci++) a += vw[c*64 + ci] * P[ci][m2];
    v[m2] = a;
  }
  float gm = gamma[0];
  #pragma unroll
  for (int n = 0; n < 4; n++){
    float o = 0.f;
    #pragma unroll
    for (int m2 = 0; m2 < 4; m2++) o += v[m2] * att[n][m2];
    g[(b*64 + c)*4 + n] = gm*o + P[c][n];
  }
}

// ---------------- 3. MFMA q,k,V producer, channel-quartered (2048 blocks) --
// bid = combo*256 + mt*4 + cq. Block computes V rows cq*16..+15 for all 64 m;
// cq==0 blocks also produce q1,q2,k1,k2.
__global__ __launch_bounds__(256, 8)
void k_qkv(const float* __restrict__ x,
           const float* __restrict__ qb, const float* __restrict__ kb,
           const float* __restrict__ vb,
           const __hip_bfloat16* __restrict__ wtv,
           const __hip_bfloat16* __restrict__ wqkb,
           float* __restrict__ qk, __hip_bfloat16* __restrict__ vt,
           u32* __restrict__ mk){
  int cq = blockIdx.x & 3; int mt = (blockIdx.x >> 2) & 63; int combo = blockIdx.x >> 8;
  int b = combo >> 2; int si = (combo >> 1) & 1; int sj = combo & 1;
  int tid = threadIdx.x; int w = tid >> 6; int lane = tid & 63;
  int l15 = lane & 15, mg = lane >> 4;

  __shared__ __attribute__((aligned(16))) unsigned char xT[8192]; // [64m][64ci] swz; reused vout[16co][64m]

  // stage x quadrant row tile -> xT (transposed, bf16, granule-swizzled)
  const float* xbase = x + (size_t)(b*64)*16384 + (si*64 + mt)*128 + sj*64;
  #pragma unroll
  for (int it = 0; it < 2; it++){
    int i = it*256 + tid;
    int a = i >> 4, q4 = i & 15;          // ci pair (2a,2a+1), m quad q4
    f32x4 r0 = *(const f32x4*)(xbase + (2*a)*16384 + 4*q4);
    f32x4 r1 = *(const f32x4*)(xbase + (2*a+1)*16384 + 4*q4);
    #pragma unroll
    for (int mm = 0; mm < 4; mm++){
      int m = 4*q4 + mm;
      u32 pk;
      asm("v_cvt_pk_bf16_f32 %0, %1, %2" : "=v"(pk) : "v"(r0[mm]), "v"(r1[mm]));
      int gs = (a >> 2) ^ (m & 7);
      *(u32*)(&xT[m*128 + gs*16 + ((4*a) & 15)]) = pk;
    }
  }
  __syncthreads();

  // B-fragments: B[ci][m], m = w*16 + l15
  int m = w*16 + l15;
  short8 bfr[2];
  #pragma unroll
  for (int ks = 0; ks < 2; ks++){
    int gs = (ks*4 + mg) ^ (m & 7);
    bfr[ks] = *(const short8*)(&xT[m*128 + gs*16]);
  }

  // qk MFMA (cq==0 blocks only)
  f32x4 aq = (f32x4){0.f,0.f,0.f,0.f};
  if (cq == 0){
    #pragma unroll
    for (int ks = 0; ks < 2; ks++){
      short8 af = *(const short8*)((const short*)wqkb + l15*64 + ks*32 + mg*8);
      aq = __builtin_amdgcn_mfma_f32_16x16x32_bf16(af, bfr[ks], aq, 0, 0, 0);
    }
  }

  // V MFMA: single co-group cq
  f32x4 av;
  {
    f32x4 acc = (f32x4){0.f,0.f,0.f,0.f};
    #pragma unroll
    for (int ks = 0; ks < 2; ks++){
      short8 af = *(const short8*)((const short*)wtv + (cq*16 + l15)*64 + ks*32 + mg*8);
      acc = __builtin_amdgcn_mfma_f32_16x16x32_bf16(af, bfr[ks], acc, 0, 0, 0);
    }
    av = acc;
  }

  // stage V quarter to LDS (reuse xT as vout[16co_local][64m] bf16, linear)
  __syncthreads();
  {
    f32x4 vbv = *(const f32x4*)(vb + cq*16 + mg*4);
    #pragma unroll
    for (int r = 0; r < 4; r++){
      int col = mg*4 + r;       // co local
      *(short*)(&xT[col*128 + m*2]) =
          (short)__bfloat16_as_ushort(__float2bfloat16(av[r] + vbv[r]));
    }
  }
  __syncthreads();

  // coalesced vt write: threads 0..127, 16 B each: row c16 = t>>3, chunk t&7
  if (tid < 128){
    int c16 = tid >> 3, ch = tid & 7;
    f32x4 v0 = *(const f32x4*)(&xT[c16*128 + ch*16]);
    __hip_bfloat16* dst = vt + (size_t)combo*64*4096 + (cq*16 + c16)*4096 + mt*64 + ch*8;
    *(f32x4*)dst = v0;
  }

  // qk epilogue (cq==0, lanes mg==0 hold rows 0..3 = q1,q2,k1,k2)
  if (cq == 0 && mg == 0){
    float q1 = (aq[0] + qb[0]) * LOG2E;
    float q2 = (aq[1] + qb[1]) * LOG2E;
    float k1 = aq[2] + kb[0];
    float k2 = aq[3] + kb[1];
    float* qkc = qk + combo*16384;
    qkc[        mt*64 + m] = q1;
    qkc[4096  + mt*64 + m] = q2;
    qkc[8192  + mt*64 + m] = k1;
    qkc[12288 + mt*64 + m] = k2;
    float a1 = fabsf(k1), a2 = fabsf(k2);
    #pragma unroll
    for (int s = 1; s < 16; s <<= 1){
      a1 = fmaxf(a1, __shfl_xor(a1, s, 64));
      a2 = fmaxf(a2, __shfl_xor(a2, s, 64));
    }
    if (l15 == 0){
      atomicMax(&mk[combo*2],     __float_as_uint(a1));
      atomicMax(&mk[combo*2 + 1], __float_as_uint(a2));
    }
  }
}

// ============ half-split flash (R14-proven) ============
#define EXP2R(x) __builtin_amdgcn_exp2f(x)

#define STAGE(BUFI, MT) do { \
    const __hip_bfloat16* srcb_ = vtc + (MT)*128; \
    _Pragma("unroll") \
    for (int i_ = 0; i_ < 4; i_++){ \
      __builtin_amdgcn_global_load_lds( \
        (const __attribute__((address_space(1))) u32*)(srcb_ + soff[i_]), \
        (__attribute__((address_space(3))) u32*)(&vbuf[BUFI][wave*1024 + i_*4096]), \
        16, 0, 0); \
    } \
    if (wave == 0){ \
      __builtin_amdgcn_global_load_lds( \
        (const __attribute__((address_space(1))) u32*)(qkc + 8192 + (MT)*128 + koff), \
        (__attribute__((address_space(3))) u32*)(&kbuf[BUFI][0]), \
        16, 0, 0); \
    } \
  } while(0)

#define CITER(BUFI, MT, DOSTAGE) do { \
    __syncthreads(); \
    if (DOSTAGE) STAGE(1-(BUFI), (MT)+1); \
    const unsigned char* kp_ = &kbuf[BUFI][0]; \
    _Pragma("unroll") \
    for (int ks_ = 0; ks_ < 4; ks_++){ \
      f32x4 ka = *(const f32x4*)(kp_ + mg32 + ks_*128); \
      f32x4 kb = *(const f32x4*)(kp_ + mg32 + ks_*128 + 16); \
      f32x4 kc = *(const f32x4*)(kp_ + 512 + mg32 + ks_*128); \
      f32x4 kd = *(const f32x4*)(kp_ + 512 + mg32 + ks_*128 + 16); \
      float e0_ = EXP2R(fmaf(q1, ka[0], fmaf(q2, kc[0], nbound))); \
      float e1_ = EXP2R(fmaf(q1, ka[1], fmaf(q2, kc[1], nbound))); \
      float e2_ = EXP2R(fmaf(q1, ka[2], fmaf(q2, kc[2], nbound))); \
      float e3_ = EXP2R(fmaf(q1, ka[3], fmaf(q2, kc[3], nbound))); \
      float f0_ = EXP2R(fmaf(q1, kb[0], fmaf(q2, kd[0], nbound))); \
      float f1_ = EXP2R(fmaf(q1, kb[1], fmaf(q2, kd[1], nbound))); \
      float f2_ = EXP2R(fmaf(q1, kb[2], fmaf(q2, kd[2], nbound))); \
      float f3_ = EXP2R(fmaf(q1, kb[3], fmaf(q2, kd[3], nbound))); \
      den += ((e0_+e1_) + (e2_+e3_)) + ((f0_+f1_) + (f2_+f3_)); \
      union { u32 w[4]; short8 v; } afu_; \
      asm("v_cvt_pk_bf16_f32 %0, %1, %2" : "=v"(afu_.w[0]) : "v"(e0_), "v"(e1_)); \
      asm("v_cvt_pk_bf16_f32 %0, %1, %2" : "=v"(afu_.w[1]) : "v"(e2_), "v"(e3_)); \
      asm("v_cvt_pk_bf16_f32 %0, %1, %2" : "=v"(afu_.w[2]) : "v"(f0_), "v"(f1_)); \
      asm("v_cvt_pk_bf16_f32 %0, %1, %2" : "=v"(afu_.w[3]) : "v"(f2_), "v"(f3_)); \
      short8 af = afu_.v; \
      _Pragma("unroll") \
      for (int cg_ = 0; cg_ < 4; cg_++){ \
        short8 bf = *(const short8*)(&vbuf[BUFI][ra[ks_*4+cg_]]); \
        acc[cg_] = __builtin_amdgcn_mfma_f32_16x16x32_bf16(af, bf, acc[cg_], 0, 0, 0); \
      } \
    } \
  } while(0)

template<int SPLIT>
__global__ __launch_bounds__(256, 4)
void k_flash(const float* __restrict__ x, const float* __restrict__ qk,
             const u32* __restrict__ mk, const __hip_bfloat16* __restrict__ vt,
             const float* __restrict__ g, const float* __restrict__ nl_gamma_p,
             __hip_bfloat16* __restrict__ ctx2b, float* __restrict__ pnum,
             float* __restrict__ pden){
  int combo, ntile, half;
  if (SPLIT){
    combo = blockIdx.x >> 7; int r = blockIdx.x & 127;
    ntile = r >> 1; half = r & 1;
  } else {
    combo = blockIdx.x >> 6; ntile = blockIdx.x & 63; half = 0;
  }
  int b = combo >> 2, si = (combo >> 1) & 1, sj = combo & 1;
  int tid = threadIdx.x; int wave = tid >> 6; int lane = tid & 63;
  int l15 = lane & 15, mg = lane >> 4;

  __shared__ __attribute__((aligned(16))) unsigned char vbuf[2][16384];
  __shared__ __attribute__((aligned(16))) unsigned char kbuf[2][1024];

  const float* qkc = qk + combo*16384;
  int n = ntile*64 + wave*16 + l15;
  float q1 = qkc[n], q2 = qkc[4096 + n];
  float nbound = -(fabsf(q1)*__uint_as_float(mk[combo*2]) +
                   fabsf(q2)*__uint_as_float(mk[combo*2+1]));

  f32x4 acc[4];
  #pragma unroll
  for (int cg = 0; cg < 4; cg++) acc[cg] = (f32x4){0.f,0.f,0.f,0.f};
  float den = 0.f;

  const __hip_bfloat16* vtc = vt + combo*64*4096;

  int ra[16];
  #pragma unroll
  for (int ks = 0; ks < 4; ks++)
    #pragma unroll
    for (int cg = 0; cg < 4; cg++){
      int c = l15 + (cg << 4);
      ra[ks*4+cg] = (c << 8) + ((((ks<<2)+mg) ^ (c & 7)) << 4);
    }
  int soff[4];
  #pragma unroll
  for (int i = 0; i < 4; i++){
    int gi = i*256 + tid;
    int row = gi >> 4, gg = gi & 15;
    int sg = gg ^ (row & 7);
    soff[i] = row*4096 + sg*8;
  }
  int koff = (lane & 31)*4 + (lane >> 5)*4096;
  int mg32 = mg*32;

  const int MT0 = SPLIT ? half*16 : 0;
  const int NP  = SPLIT ? 8 : 16;

  STAGE(0, MT0);
  #pragma unroll 1
  for (int mt2 = 0; mt2 < NP; mt2++){
    CITER(0, MT0 + mt2*2,     1);
    CITER(1, MT0 + mt2*2 + 1, (mt2 < NP-1));
  }

  den += __shfl_xor(den, 16, 64);
  den += __shfl_xor(den, 32, 64);

  if (SPLIT){
    int tile = (half*8 + combo)*64 + ntile;
    #pragma unroll
    for (int cg = 0; cg < 4; cg++){
      int c = l15 + (cg << 4);
      float* pn = pnum + tile*4096 + c*64 + wave*16 + mg*4;
      *(f32x4*)pn = acc[cg];
    }
    if (mg == 0) pden[tile*64 + wave*16 + l15] = den;
  } else {
    float inv = 1.f / den;
    float invj[4];
    #pragma unroll
    for (int j = 0; j < 4; j++) invj[j] = __shfl(inv, mg*4 + j, 64);

    float nlg = nl_gamma_p[0];
    int Y  = si*64 + ntile;
    int X0 = sj*64 + wave*16 + mg*4;
    float fy = Y * (1.f/127.f);
    #pragma unroll
    for (int cg = 0; cg < 4; cg++){
      int c = l15 + (cg << 4);
      f32x4 gv = *(const f32x4*)(g + (b*64 + c)*4);
      float top_l = gv[0] + fy*(gv[2] - gv[0]);
      float top_r = gv[1] + fy*(gv[3] - gv[1]);
      const float* xrow = x + ((b*64 + c)*128 + Y)*128 + X0;
      f32x4 xv = *(const f32x4*)xrow;
      f32x4 o;
      #pragma unroll
      for (int j = 0; j < 4; j++){
        float val = acc[cg][j] * invj[j];
        float ctx = fmaf(nlg, val, xv[j]);
        float fx = (X0 + j) * (1.f/127.f);
        float gg = top_l + fx*(top_r - top_l);
        float gate = 1.f / (1.f + __expf(-gg));
        o[j] = ctx * gate;
      }
      u32 pk0, pk1;
      asm("v_cvt_pk_bf16_f32 %0, %1, %2" : "=v"(pk0) : "v"(o[0]), "v"(o[1]));
      asm("v_cvt_pk_bf16_f32 %0, %1, %2" : "=v"(pk1) : "v"(o[2]), "v"(o[3]));
      u32* dst = (u32*)(ctx2b + (b*64 + c)*16384 + Y*128 + X0);
      dst[0] = pk0; dst[1] = pk1;
    }
  }
}

// ---------------- 4b. combine halves + normalize + gate (bf16 out) --------
template<int S>
__global__ __launch_bounds__(256)
void k_combine(const float* __restrict__ pnum, const float* __restrict__ pden,
               const float* __restrict__ x, const float* __restrict__ g,
               const float* __restrict__ nl_gamma_p, __hip_bfloat16* __restrict__ ctx2b){
  int bid = blockIdx.x; int combo = bid >> 6; int nt = bid & 63;
  int b = combo >> 2, si = (combo >> 1) & 1, sj = combo & 1;
  int tid = threadIdx.x; int c = tid >> 2; int nq = tid & 3;
  int tile0 = combo*64 + nt;
  float inv[16];
  #pragma unroll
  for (int q = 0; q < 4; q++){
    f32x4 dsum = (f32x4){0.f,0.f,0.f,0.f};
    #pragma unroll
    for (int p = 0; p < S; p++){
      f32x4 d = *(const f32x4*)(pden + (tile0 + p*512)*64 + nq*16 + q*4);
      #pragma unroll
      for (int j = 0; j < 4; j++) dsum[j] += d[j];
    }
    #pragma unroll
    for (int j = 0; j < 4; j++) inv[q*4+j] = 1.f / fmaxf(dsum[j], 1e-30f);
  }
  int Y = si*64 + nt; int X0 = sj*64 + nq*16;
  float fy = Y * (1.f/127.f);
  f32x4 gv = *(const f32x4*)(g + (b*64 + c)*4);
  float top_l = gv[0] + fy*(gv[2] - gv[0]);
  float top_r = gv[1] + fy*(gv[3] - gv[1]);
  float nlg = nl_gamma_p[0];
  const float* xrow = x + ((b*64 + c)*128 + Y)*128 + X0;
  __hip_bfloat16* orow = ctx2b + ((b*64 + c)*128 + Y)*128 + X0;
  #pragma unroll
  for (int q = 0; q < 4; q++){
    f32x4 xv = *(const f32x4*)(xrow + q*4);
    f32x4 nsum = (f32x4){0.f,0.f,0.f,0.f};
    #pragma unroll
    for (int p = 0; p < S; p++){
      f32x4 nv = *(const f32x4*)(pnum + (size_t)(tile0 + p*512)*4096 + c*64 + nq*16 + q*4);
      #pragma unroll
      for (int j = 0; j < 4; j++) nsum[j] += nv[j];
    }
    f32x4 o;
    #pragma unroll
    for (int j = 0; j < 4; j++){
      float val = nsum[j] * inv[q*4 + j];
      float ctx = fmaf(nlg, val, xv[j]);
      float fx = (X0 + q*4 + j) * (1.f/127.f);
      float gg = top_l + fx*(top_r - top_l);
      o[j] = ctx / (1.f + __expf(-gg));
    }
    u32 pk0, pk1;
    asm("v_cvt_pk_bf16_f32 %0, %1, %2" : "=v"(pk0) : "v"(o[0]), "v"(o[1]));
    asm("v_cvt_pk_bf16_f32 %0, %1, %2" : "=v"(pk1) : "v"(o[2]), "v"(o[3]));
    u32* dst = (u32*)(orow + q*4);
    dst[0] = pk0; dst[1] = pk1;
  }
}

// ---------------- 5. MFMA 3x3 conv (9 shifted 1x1 GEMMs) + BN + relu ------
__global__ __launch_bounds__(256, 2)
void k_conv(const __hip_bfloat16* __restrict__ ctx2b,
            const __hip_bfloat16* __restrict__ wtb,
            const float* __restrict__ cb, const float* __restrict__ bnw,
            const float* __restrict__ bnb, const float* __restrict__ bnm,
            const float* __restrict__ bnv, const float* __restrict__ gp,
            const float* __restrict__ x, float* __restrict__ out){
  int xh = blockIdx.x & 1; int y = (blockIdx.x >> 1) & 127; int b = blockIdx.x >> 8;
  int xbase = xh*64;
  int tid = threadIdx.x; int w = tid >> 6; int lane = tid & 63;
  int l15 = lane & 15, mg = lane >> 4;

  __shared__ __attribute__((aligned(16))) unsigned char ldsT[25344]; // [3][66][64ci] bf16

  for (int t = tid; t < 1584; t += 256){      // 3*66*8 granules
    int r = t / 528; int rem = t - r*528; int q = rem >> 3; int gg = rem & 7;
    int gy = y + r - 1; int gx = xbase + q - 1;
    short8 val = (short8){0,0,0,0,0,0,0,0};
    if (gy >= 0 && gy < 128 && gx >= 0 && gx < 128){
      const short* src = (const short*)(ctx2b + (b*64 + gg*8)*16384 + gy*128 + gx);
      #pragma unroll
      for (int i = 0; i < 8; i++) val[i] = src[i*16384];
    }
    int gs = gg ^ (q & 7);
    *(short8*)(&ldsT[(r*66 + q)*128 + gs*16]) = val;
  }
  __syncthreads();

  f32x4 acc[4];
  #pragma unroll
  for (int p = 0; p < 4; p++) acc[p] = (f32x4){0.f,0.f,0.f,0.f};

  const short* wv = (const short*)wtb + (w*16 + l15)*64 + mg*8;
  #pragma unroll
  for (int tap = 0; tap < 9; tap++){
    const int r3 = tap / 3, dx = tap % 3;
    #pragma unroll
    for (int h = 0; h < 2; h++){
      short8 af = *(const short8*)(wv + tap*4096 + h*32);
      #pragma unroll
      for (int p = 0; p < 4; p++){
        int q = p*16 + l15 + dx;
        int gs = ((h << 2) + mg) ^ (q & 7);
        short8 bf = *(const short8*)(&ldsT[(r3*66 + q)*128 + gs*16]);
        acc[p] = __builtin_amdgcn_mfma_f32_16x16x32_bf16(af, bf, acc[p], 0, 0, 0);
      }
    }
  }

  float gam = gp[0];
  #pragma unroll
  for (int r = 0; r < 4; r++){
    int co = w*16 + mg*4 + r;
    float scale = bnw[co] * rsqrtf(bnv[co] + 1e-5f);
    float shift = bnb[co] - bnm[co]*scale;
    float cbv = cb[co];
    const float* xrow = x + (b*64 + co)*16384 + y*128 + xbase;
    float* orow = out + (b*64 + co)*16384 + y*128 + xbase;
    #pragma unroll
    for (int p = 0; p < 4; p++){
      int px = p*16 + l15;
      float t = (acc[p][r] + cbv)*scale + shift;
      orow[px] = fmaxf(fmaf(gam, t, xrow[px]), 0.f);
    }
  }
}

extern "C" void kernel_launch(void* const* d_in, const int* in_sizes, int n_in,
                              void* d_out, int out_size, void* d_ws, size_t ws_size,
                              hipStream_t stream) {
  const float* x        = (const float*)d_in[0];
  const float* nl_q_w   = (const float*)d_in[1];
  const float* nl_q_b   = (const float*)d_in[2];
  const float* nl_k_w   = (const float*)d_in[3];
  const float* nl_k_b   = (const float*)d_in[4];
  const float* nl_v_w   = (const float*)d_in[5];
  const float* nl_v_b   = (const float*)d_in[6];
  const float* nl_gamma = (const float*)d_in[7];
  const float* gq_w     = (const float*)d_in[8];
  const float* gq_b     = (const float*)d_in[9];
  const float* gk_w     = (const float*)d_in[10];
  const float* gk_b     = (const float*)d_in[11];
  const float* gv_w     = (const float*)d_in[12];
  const float* gv_b     = (const float*)d_in[13];
  const float* g_gamma  = (const float*)d_in[14];
  const float* conv_w   = (const float*)d_in[15];
  const float* conv_b   = (const float*)d_in[16];
  const float* bn_w     = (const float*)d_in[17];
  const float* bn_b     = (const float*)d_in[18];
  const float* bn_mean  = (const float*)d_in[19];
  const float* bn_var   = (const float*)d_in[20];
  const float* gamma    = (const float*)d_in[21];
  float* out = (float*)d_out;

  float* ws = (float*)d_ws;
  float* pool = ws + WS_POOL;
  float* g    = ws + WS_G;
  float* qk   = ws + WS_QK;
  u32*   mk   = (u32*)(ws + WS_MK);
  __hip_bfloat16* vt   = (__hip_bfloat16*)(ws + WS_VT);
  __hip_bfloat16* wtb  = (__hip_bfloat16*)(ws + WS_WT);
  __hip_bfloat16* wtv  = (__hip_bfloat16*)(ws + WS_WTV);
  __hip_bfloat16* wqkb = (__hip_bfloat16*)(ws + WS_WQK);
  __hip_bfloat16* ctx2b= (__hip_bfloat16*)(ws + WS_CTX);
  float* pden = ws + WS_PDEN;
  float* pnum = ws + WS_PNUM2;

  k_pool<<<512, 256, 0, stream>>>(x, pool, mk);
  k_gca_wt<<<166, 256, 0, stream>>>(pool, gq_w, gq_b, gk_w, gk_b, gv_w, gv_b,
                                    g_gamma, g, conv_w, wtb, wtv, wqkb);
  k_qkv<<<2048, 256, 0, stream>>>(x, nl_q_b, nl_k_b, nl_v_b, wtv, wqkb,
                                  qk, vt, mk);
  if (ws_size >= WS_SPLIT2_BYTES){
    k_flash<1><<<1024, 256, 0, stream>>>(x, qk, mk, vt, g, nl_gamma, ctx2b, pnum, pden);
    k_combine<2><<<512, 256, 0, stream>>>(pnum, pden, x, g, nl_gamma, ctx2b);
  } else {
    k_flash<0><<<512, 256, 0, stream>>>(x, qk, mk, vt, g, nl_gamma, ctx2b, pnum, pden);
  }
  k_conv<<<512, 256, 0, stream>>>(ctx2b, wtb, conv_b, bn_w, bn_b, bn_mean,
                                  bn_var, gamma, x, out);
}

// Round 18
// 126.720 us; speedup vs baseline: 1.1793x; 1.1793x over previous
//
#include <hip/hip_runtime.h>
#include <hip/hip_bf16.h>

typedef float f32x4 __attribute__((ext_vector_type(4)));
typedef short short8 __attribute__((ext_vector_type(8)));
typedef unsigned int u32;

#define LOG2E 1.44269504088896f

// ---------------- ws layout (float offsets) ----------------
#define WS_POOL 0
#define WS_G    1024
#define WS_QK   2048
#define WS_MK   133120
#define WS_VT   134144
#define WS_WT   1182720            // bf16 [tap][co][ci] 36864 elems
#define WS_CTX  1219584            // bf16 [b][c][y][x] 2097152 elems
#define WS_PDEN 3316736            // f32 [1024 tiles][64]
#define WS_PNUM2 3382272           // f32 [1024 tiles][4096]
#define WS_SPLIT2_BYTES ((size_t)(WS_PNUM2 + 4194304) * 4)

// ---------------- 1. adaptive max pool 128x128 -> 2x2 (+ mk zero-init) ----
__global__ void k_pool(const float* __restrict__ x, float* __restrict__ pool,
                       u32* __restrict__ mk){
  if (blockIdx.x == 0 && threadIdx.x < 16) mk[threadIdx.x] = 0u;
  int bid = blockIdx.x;            // ((b*64+c)*4 + t)
  int t4 = bid & 3; int c = (bid >> 2) & 63; int b = bid >> 8;
  int i = t4 >> 1, j = t4 & 1;
  const float* base = x + (((b*64 + c)*128) + i*64)*128 + j*64;
  int tid = threadIdx.x;
  float m = -3.402823466e38f;
  for (int k = tid; k < 4096; k += 256){
    int r = k >> 6, cc = k & 63;
    m = fmaxf(m, base[r*128 + cc]);
  }
  __shared__ float red[256];
  red[tid] = m; __syncthreads();
  for (int s = 128; s > 0; s >>= 1){
    if (tid < s) red[tid] = fmaxf(red[tid], red[tid + s]);
    __syncthreads();
  }
  if (tid == 0) pool[bid] = red[0];
}

// ---------------- 2. tiny non-local on pooled 2x2  +  conv-weight transform
__global__ void k_gca_wt(const float* __restrict__ pool,
                      const float* qw, const float* qb,
                      const float* kw, const float* kb,
                      const float* vw, const float* vb,
                      const float* gamma, float* __restrict__ g,
                      const float* __restrict__ w, __hip_bfloat16* __restrict__ wtb){
  if (blockIdx.x >= 2){
    int idx = (int)(blockIdx.x - 2)*256 + threadIdx.x;   // 36864 total
    if (idx < 36864){
      int ci = idx & 63; int t2 = idx >> 6; int co = t2 & 63; int tap = t2 >> 6;
      wtb[idx] = __float2bfloat16(w[(co*64 + ci)*9 + tap]);
    }
    return;
  }
  int b = blockIdx.x; int c = threadIdx.x;
  __shared__ float P[64][4];
  if (c < 64){
    #pragma unroll
    for (int t = 0; t < 4; t++) P[c][t] = pool[(b*64 + c)*4 + t];
  }
  __syncthreads();
  if (c >= 64) return;
  float q[2][4], kk[2][4];
  #pragma unroll
  for (int i = 0; i < 2; i++)
    #pragma unroll
    for (int n = 0; n < 4; n++){
      float a = qb[i], e = kb[i];
      for (int ci = 0; ci < 64; ci++){
        a += qw[i*64 + ci] * P[ci][n];
        e += kw[i*64 + ci] * P[ci][n];
      }
      q[i][n] = a; kk[i][n] = e;
    }
  float att[4][4];
  #pragma unroll
  for (int n = 0; n < 4; n++){
    float mx = -3.402823466e38f;
    #pragma unroll
    for (int m2 = 0; m2 < 4; m2++){
      att[n][m2] = q[0][n]*kk[0][m2] + q[1][n]*kk[1][m2];
      mx = fmaxf(mx, att[n][m2]);
    }
    float s = 0.f;
    #pragma unroll
    for (int m2 = 0; m2 < 4; m2++){ att[n][m2] = __expf(att[n][m2] - mx); s += att[n][m2]; }
    float inv = 1.f / s;
    #pragma unroll
    for (int m2 = 0; m2 < 4; m2++) att[n][m2] *= inv;
  }
  float v[4];
  #pragma unroll
  for (int m2 = 0; m2 < 4; m2++){
    float a = vb[c];
    for (int ci = 0; ci < 64; ci++) a += vw[c*64 + ci] * P[ci][m2];
    v[m2] = a;
  }
  float gm = gamma[0];
  #pragma unroll
  for (int n = 0; n < 4; n++){
    float o = 0.f;
    #pragma unroll
    for (int m2 = 0; m2 < 4; m2++) o += v[m2] * att[n][m2];
    g[(b*64 + c)*4 + n] = gm*o + P[c][n];
  }
}

// ---------------- 3a. q,k producer (R14 structure, V removed) -------------
__global__ __launch_bounds__(256, 8)
void k_qk(const float* __restrict__ x,
          const float* __restrict__ qw, const float* __restrict__ qb,
          const float* __restrict__ kw, const float* __restrict__ kb,
          float* __restrict__ qk, u32* __restrict__ mk){
  int mt = blockIdx.x & 63; int combo = blockIdx.x >> 6;
  int b = combo >> 2; int si = (combo >> 1) & 1; int sj = combo & 1;
  int tid = threadIdx.x; int w = tid >> 6; int m = tid & 63;

  __shared__ __attribute__((aligned(16))) float x_lds[64][64];

  const float* xbase = x + (b*64)*16384 + (si*64 + mt)*128 + sj*64;
  #pragma unroll
  for (int k = 0; k < 4; k++){
    int idx = k*256 + tid;
    int row = idx >> 4, c4 = idx & 15;
    f32x4 v = *(const f32x4*)(xbase + row*16384 + c4*4);
    *(f32x4*)(&x_lds[row][c4*4]) = v;
  }
  __syncthreads();

  const float* wsel = (w == 0) ? qw : (w == 1) ? (qw + 64) : (w == 2) ? kw : (kw + 64);
  float bias = (w == 0) ? qb[0] : (w == 1) ? qb[1] : (w == 2) ? kb[0] : kb[1];
  float qkv_ = bias;
  for (int ci = 0; ci < 64; ci++) qkv_ = fmaf(wsel[ci], x_lds[ci][m], qkv_);
  float scale = (w < 2) ? LOG2E : 1.0f;
  qk[combo*16384 + w*4096 + mt*64 + m] = qkv_ * scale;
  if (w >= 2){
    float av = fabsf(qkv_);
    #pragma unroll
    for (int s = 1; s < 64; s <<= 1) av = fmaxf(av, __shfl_xor(av, s, 64));
    if (m == 0) atomicMax(&mk[combo*2 + (w - 2)], __float_as_uint(av));
  }
}

// ---------------- 3b. V producer (R14 structure, qk removed) --------------
__global__ __launch_bounds__(256, 8)
void k_v(const float* __restrict__ x,
         const float* __restrict__ vw, const float* __restrict__ vb,
         __hip_bfloat16* __restrict__ vt){
  int mt = blockIdx.x & 63; int combo = blockIdx.x >> 6;
  int b = combo >> 2; int si = (combo >> 1) & 1; int sj = combo & 1;
  int tid = threadIdx.x; int w = tid >> 6; int m = tid & 63;

  __shared__ __attribute__((aligned(16))) float x_lds[64][64];

  const float* xbase = x + (b*64)*16384 + (si*64 + mt)*128 + sj*64;
  #pragma unroll
  for (int k = 0; k < 4; k++){
    int idx = k*256 + tid;
    int row = idx >> 4, c4 = idx & 15;
    f32x4 v = *(const f32x4*)(xbase + row*16384 + c4*4);
    *(f32x4*)(&x_lds[row][c4*4]) = v;
  }
  __syncthreads();

  float acc[16];
  #pragma unroll
  for (int k = 0; k < 16; k++) acc[k] = vb[w*16 + k];
  for (int ci = 0; ci < 64; ci++){
    float xv = x_lds[ci][m];
    const float* wr = vw + ci;
    #pragma unroll
    for (int k = 0; k < 16; k++)
      acc[k] = fmaf(wr[(w*16 + k)*64], xv, acc[k]);
  }
  __hip_bfloat16* vtc = vt + (size_t)combo*64*4096 + mt*64 + m;
  #pragma unroll
  for (int k = 0; k < 16; k++)
    vtc[(w*16 + k)*4096] = __float2bfloat16(acc[k]);
}

// ============ half-split flash (R14-proven, exp2-direct) ============
#define EXP2R(x) __builtin_amdgcn_exp2f(x)

#define STAGE(BUFI, MT) do { \
    const __hip_bfloat16* srcb_ = vtc + (MT)*128; \
    _Pragma("unroll") \
    for (int i_ = 0; i_ < 4; i_++){ \
      __builtin_amdgcn_global_load_lds( \
        (const __attribute__((address_space(1))) u32*)(srcb_ + soff[i_]), \
        (__attribute__((address_space(3))) u32*)(&vbuf[BUFI][wave*1024 + i_*4096]), \
        16, 0, 0); \
    } \
    if (wave == 0){ \
      __builtin_amdgcn_global_load_lds( \
        (const __attribute__((address_space(1))) u32*)(qkc + 8192 + (MT)*128 + koff), \
        (__attribute__((address_space(3))) u32*)(&kbuf[BUFI][0]), \
        16, 0, 0); \
    } \
  } while(0)

#define CITER(BUFI, MT, DOSTAGE) do { \
    __syncthreads(); \
    if (DOSTAGE) STAGE(1-(BUFI), (MT)+1); \
    const unsigned char* kp_ = &kbuf[BUFI][0]; \
    _Pragma("unroll") \
    for (int ks_ = 0; ks_ < 4; ks_++){ \
      f32x4 ka = *(const f32x4*)(kp_ + mg32 + ks_*128); \
      f32x4 kb = *(const f32x4*)(kp_ + mg32 + ks_*128 + 16); \
      f32x4 kc = *(const f32x4*)(kp_ + 512 + mg32 + ks_*128); \
      f32x4 kd = *(const f32x4*)(kp_ + 512 + mg32 + ks_*128 + 16); \
      float e0_ = EXP2R(fmaf(q1, ka[0], fmaf(q2, kc[0], nbound))); \
      float e1_ = EXP2R(fmaf(q1, ka[1], fmaf(q2, kc[1], nbound))); \
      float e2_ = EXP2R(fmaf(q1, ka[2], fmaf(q2, kc[2], nbound))); \
      float e3_ = EXP2R(fmaf(q1, ka[3], fmaf(q2, kc[3], nbound))); \
      float f0_ = EXP2R(fmaf(q1, kb[0], fmaf(q2, kd[0], nbound))); \
      float f1_ = EXP2R(fmaf(q1, kb[1], fmaf(q2, kd[1], nbound))); \
      float f2_ = EXP2R(fmaf(q1, kb[2], fmaf(q2, kd[2], nbound))); \
      float f3_ = EXP2R(fmaf(q1, kb[3], fmaf(q2, kd[3], nbound))); \
      den += ((e0_+e1_) + (e2_+e3_)) + ((f0_+f1_) + (f2_+f3_)); \
      union { u32 w[4]; short8 v; } afu_; \
      asm("v_cvt_pk_bf16_f32 %0, %1, %2" : "=v"(afu_.w[0]) : "v"(e0_), "v"(e1_)); \
      asm("v_cvt_pk_bf16_f32 %0, %1, %2" : "=v"(afu_.w[1]) : "v"(e2_), "v"(e3_)); \
      asm("v_cvt_pk_bf16_f32 %0, %1, %2" : "=v"(afu_.w[2]) : "v"(f0_), "v"(f1_)); \
      asm("v_cvt_pk_bf16_f32 %0, %1, %2" : "=v"(afu_.w[3]) : "v"(f2_), "v"(f3_)); \
      short8 af = afu_.v; \
      _Pragma("unroll") \
      for (int cg_ = 0; cg_ < 4; cg_++){ \
        short8 bf = *(const short8*)(&vbuf[BUFI][ra[ks_*4+cg_]]); \
        acc[cg_] = __builtin_amdgcn_mfma_f32_16x16x32_bf16(af, bf, acc[cg_], 0, 0, 0); \
      } \
    } \
  } while(0)

template<int SPLIT>
__global__ __launch_bounds__(256, 4)
void k_flash(const float* __restrict__ x, const float* __restrict__ qk,
             const u32* __restrict__ mk, const __hip_bfloat16* __restrict__ vt,
             const float* __restrict__ g, const float* __restrict__ nl_gamma_p,
             __hip_bfloat16* __restrict__ ctx2b, float* __restrict__ pnum,
             float* __restrict__ pden){
  int combo, ntile, half;
  if (SPLIT){
    combo = blockIdx.x >> 7; int r = blockIdx.x & 127;
    ntile = r >> 1; half = r & 1;
  } else {
    combo = blockIdx.x >> 6; ntile = blockIdx.x & 63; half = 0;
  }
  int b = combo >> 2, si = (combo >> 1) & 1, sj = combo & 1;
  int tid = threadIdx.x; int wave = tid >> 6; int lane = tid & 63;
  int l15 = lane & 15, mg = lane >> 4;

  __shared__ __attribute__((aligned(16))) unsigned char vbuf[2][16384];
  __shared__ __attribute__((aligned(16))) unsigned char kbuf[2][1024];

  const float* qkc = qk + combo*16384;
  int n = ntile*64 + wave*16 + l15;
  float q1 = qkc[n], q2 = qkc[4096 + n];
  float nbound = -(fabsf(q1)*__uint_as_float(mk[combo*2]) +
                   fabsf(q2)*__uint_as_float(mk[combo*2+1]));

  f32x4 acc[4];
  #pragma unroll
  for (int cg = 0; cg < 4; cg++) acc[cg] = (f32x4){0.f,0.f,0.f,0.f};
  float den = 0.f;

  const __hip_bfloat16* vtc = vt + combo*64*4096;

  int ra[16];
  #pragma unroll
  for (int ks = 0; ks < 4; ks++)
    #pragma unroll
    for (int cg = 0; cg < 4; cg++){
      int c = l15 + (cg << 4);
      ra[ks*4+cg] = (c << 8) + ((((ks<<2)+mg) ^ (c & 7)) << 4);
    }
  int soff[4];
  #pragma unroll
  for (int i = 0; i < 4; i++){
    int gi = i*256 + tid;
    int row = gi >> 4, gg = gi & 15;
    int sg = gg ^ (row & 7);
    soff[i] = row*4096 + sg*8;
  }
  int koff = (lane & 31)*4 + (lane >> 5)*4096;
  int mg32 = mg*32;

  const int MT0 = SPLIT ? half*16 : 0;
  const int NP  = SPLIT ? 8 : 16;

  STAGE(0, MT0);
  #pragma unroll 1
  for (int mt2 = 0; mt2 < NP; mt2++){
    CITER(0, MT0 + mt2*2,     1);
    CITER(1, MT0 + mt2*2 + 1, (mt2 < NP-1));
  }

  den += __shfl_xor(den, 16, 64);
  den += __shfl_xor(den, 32, 64);

  if (SPLIT){
    int tile = (half*8 + combo)*64 + ntile;
    #pragma unroll
    for (int cg = 0; cg < 4; cg++){
      int c = l15 + (cg << 4);
      float* pn = pnum + tile*4096 + c*64 + wave*16 + mg*4;
      *(f32x4*)pn = acc[cg];
    }
    if (mg == 0) pden[tile*64 + wave*16 + l15] = den;
  } else {
    float inv = 1.f / den;
    float invj[4];
    #pragma unroll
    for (int j = 0; j < 4; j++) invj[j] = __shfl(inv, mg*4 + j, 64);

    float nlg = nl_gamma_p[0];
    int Y  = si*64 + ntile;
    int X0 = sj*64 + wave*16 + mg*4;
    float fy = Y * (1.f/127.f);
    #pragma unroll
    for (int cg = 0; cg < 4; cg++){
      int c = l15 + (cg << 4);
      f32x4 gv = *(const f32x4*)(g + (b*64 + c)*4);
      float top_l = gv[0] + fy*(gv[2] - gv[0]);
      float top_r = gv[1] + fy*(gv[3] - gv[1]);
      const float* xrow = x + ((b*64 + c)*128 + Y)*128 + X0;
      f32x4 xv = *(const f32x4*)xrow;
      f32x4 o;
      #pragma unroll
      for (int j = 0; j < 4; j++){
        float val = acc[cg][j] * invj[j];
        float ctx = fmaf(nlg, val, xv[j]);
        float fx = (X0 + j) * (1.f/127.f);
        float gg = top_l + fx*(top_r - top_l);
        float gate = 1.f / (1.f + __expf(-gg));
        o[j] = ctx * gate;
      }
      u32 pk0, pk1;
      asm("v_cvt_pk_bf16_f32 %0, %1, %2" : "=v"(pk0) : "v"(o[0]), "v"(o[1]));
      asm("v_cvt_pk_bf16_f32 %0, %1, %2" : "=v"(pk1) : "v"(o[2]), "v"(o[3]));
      u32* dst = (u32*)(ctx2b + (b*64 + c)*16384 + Y*128 + X0);
      dst[0] = pk0; dst[1] = pk1;
    }
  }
}

// ---------------- 4b. combine halves + normalize + gate (bf16 out) --------
template<int S>
__global__ __launch_bounds__(256)
void k_combine(const float* __restrict__ pnum, const float* __restrict__ pden,
               const float* __restrict__ x, const float* __restrict__ g,
               const float* __restrict__ nl_gamma_p, __hip_bfloat16* __restrict__ ctx2b){
  int bid = blockIdx.x; int combo = bid >> 6; int nt = bid & 63;
  int b = combo >> 2, si = (combo >> 1) & 1, sj = combo & 1;
  int tid = threadIdx.x; int c = tid >> 2; int nq = tid & 3;
  int tile0 = combo*64 + nt;
  float inv[16];
  #pragma unroll
  for (int q = 0; q < 4; q++){
    f32x4 dsum = (f32x4){0.f,0.f,0.f,0.f};
    #pragma unroll
    for (int p = 0; p < S; p++){
      f32x4 d = *(const f32x4*)(pden + (tile0 + p*512)*64 + nq*16 + q*4);
      #pragma unroll
      for (int j = 0; j < 4; j++) dsum[j] += d[j];
    }
    #pragma unroll
    for (int j = 0; j < 4; j++) inv[q*4+j] = 1.f / fmaxf(dsum[j], 1e-30f);
  }
  int Y = si*64 + nt; int X0 = sj*64 + nq*16;
  float fy = Y * (1.f/127.f);
  f32x4 gv = *(const f32x4*)(g + (b*64 + c)*4);
  float top_l = gv[0] + fy*(gv[2] - gv[0]);
  float top_r = gv[1] + fy*(gv[3] - gv[1]);
  float nlg = nl_gamma_p[0];
  const float* xrow = x + ((b*64 + c)*128 + Y)*128 + X0;
  __hip_bfloat16* orow = ctx2b + ((b*64 + c)*128 + Y)*128 + X0;
  #pragma unroll
  for (int q = 0; q < 4; q++){
    f32x4 xv = *(const f32x4*)(xrow + q*4);
    f32x4 nsum = (f32x4){0.f,0.f,0.f,0.f};
    #pragma unroll
    for (int p = 0; p < S; p++){
      f32x4 nv = *(const f32x4*)(pnum + (size_t)(tile0 + p*512)*4096 + c*64 + nq*16 + q*4);
      #pragma unroll
      for (int j = 0; j < 4; j++) nsum[j] += nv[j];
    }
    f32x4 o;
    #pragma unroll
    for (int j = 0; j < 4; j++){
      float val = nsum[j] * inv[q*4 + j];
      float ctx = fmaf(nlg, val, xv[j]);
      float fx = (X0 + q*4 + j) * (1.f/127.f);
      float gg = top_l + fx*(top_r - top_l);
      o[j] = ctx / (1.f + __expf(-gg));
    }
    u32 pk0, pk1;
    asm("v_cvt_pk_bf16_f32 %0, %1, %2" : "=v"(pk0) : "v"(o[0]), "v"(o[1]));
    asm("v_cvt_pk_bf16_f32 %0, %1, %2" : "=v"(pk1) : "v"(o[2]), "v"(o[3]));
    u32* dst = (u32*)(orow + q*4);
    dst[0] = pk0; dst[1] = pk1;
  }
}

// ---------------- 5. MFMA 3x3 conv (9 shifted 1x1 GEMMs) + BN + relu ------
__global__ __launch_bounds__(256, 2)
void k_conv(const __hip_bfloat16* __restrict__ ctx2b,
            const __hip_bfloat16* __restrict__ wtb,
            const float* __restrict__ cb, const float* __restrict__ bnw,
            const float* __restrict__ bnb, const float* __restrict__ bnm,
            const float* __restrict__ bnv, const float* __restrict__ gp,
            const float* __restrict__ x, float* __restrict__ out){
  int xh = blockIdx.x & 1; int y = (blockIdx.x >> 1) & 127; int b = blockIdx.x >> 8;
  int xbase = xh*64;
  int tid = threadIdx.x; int w = tid >> 6; int lane = tid & 63;
  int l15 = lane & 15, mg = lane >> 4;

  __shared__ __attribute__((aligned(16))) unsigned char ldsT[25344]; // [3][66][64ci] bf16

  for (int t = tid; t < 1584; t += 256){      // 3*66*8 granules
    int r = t / 528; int rem = t - r*528; int q = rem >> 3; int gg = rem & 7;
    int gy = y + r - 1; int gx = xbase + q - 1;
    short8 val = (short8){0,0,0,0,0,0,0,0};
    if (gy >= 0 && gy < 128 && gx >= 0 && gx < 128){
      const short* src = (const short*)(ctx2b + (b*64 + gg*8)*16384 + gy*128 + gx);
      #pragma unroll
      for (int i = 0; i < 8; i++) val[i] = src[i*16384];
    }
    int gs = gg ^ (q & 7);
    *(short8*)(&ldsT[(r*66 + q)*128 + gs*16]) = val;
  }
  __syncthreads();

  f32x4 acc[4];
  #pragma unroll
  for (int p = 0; p < 4; p++) acc[p] = (f32x4){0.f,0.f,0.f,0.f};

  const short* wv = (const short*)wtb + (w*16 + l15)*64 + mg*8;
  #pragma unroll
  for (int tap = 0; tap < 9; tap++){
    const int r3 = tap / 3, dx = tap % 3;
    #pragma unroll
    for (int h = 0; h < 2; h++){
      short8 af = *(const short8*)(wv + tap*4096 + h*32);
      #pragma unroll
      for (int p = 0; p < 4; p++){
        int q = p*16 + l15 + dx;
        int gs = ((h << 2) + mg) ^ (q & 7);
        short8 bf = *(const short8*)(&ldsT[(r3*66 + q)*128 + gs*16]);
        acc[p] = __builtin_amdgcn_mfma_f32_16x16x32_bf16(af, bf, acc[p], 0, 0, 0);
      }
    }
  }

  float gam = gp[0];
  #pragma unroll
  for (int r = 0; r < 4; r++){
    int co = w*16 + mg*4 + r;
    float scale = bnw[co] * rsqrtf(bnv[co] + 1e-5f);
    float shift = bnb[co] - bnm[co]*scale;
    float cbv = cb[co];
    const float* xrow = x + (b*64 + co)*16384 + y*128 + xbase;
    float* orow = out + (b*64 + co)*16384 + y*128 + xbase;
    #pragma unroll
    for (int p = 0; p < 4; p++){
      int px = p*16 + l15;
      float t = (acc[p][r] + cbv)*scale + shift;
      orow[px] = fmaxf(fmaf(gam, t, xrow[px]), 0.f);
    }
  }
}

extern "C" void kernel_launch(void* const* d_in, const int* in_sizes, int n_in,
                              void* d_out, int out_size, void* d_ws, size_t ws_size,
                              hipStream_t stream) {
  const float* x        = (const float*)d_in[0];
  const float* nl_q_w   = (const float*)d_in[1];
  const float* nl_q_b   = (const float*)d_in[2];
  const float* nl_k_w   = (const float*)d_in[3];
  const float* nl_k_b   = (const float*)d_in[4];
  const float* nl_v_w   = (const float*)d_in[5];
  const float* nl_v_b   = (const float*)d_in[6];
  const float* nl_gamma = (const float*)d_in[7];
  const float* gq_w     = (const float*)d_in[8];
  const float* gq_b     = (const float*)d_in[9];
  const float* gk_w     = (const float*)d_in[10];
  const float* gk_b     = (const float*)d_in[11];
  const float* gv_w     = (const float*)d_in[12];
  const float* gv_b     = (const float*)d_in[13];
  const float* g_gamma  = (const float*)d_in[14];
  const float* conv_w   = (const float*)d_in[15];
  const float* conv_b   = (const float*)d_in[16];
  const float* bn_w     = (const float*)d_in[17];
  const float* bn_b     = (const float*)d_in[18];
  const float* bn_mean  = (const float*)d_in[19];
  const float* bn_var   = (const float*)d_in[20];
  const float* gamma    = (const float*)d_in[21];
  float* out = (float*)d_out;

  float* ws = (float*)d_ws;
  float* pool = ws + WS_POOL;
  float* g    = ws + WS_G;
  float* qk   = ws + WS_QK;
  u32*   mk   = (u32*)(ws + WS_MK);
  __hip_bfloat16* vt   = (__hip_bfloat16*)(ws + WS_VT);
  __hip_bfloat16* wtb  = (__hip_bfloat16*)(ws + WS_WT);
  __hip_bfloat16* ctx2b= (__hip_bfloat16*)(ws + WS_CTX);
  float* pden = ws + WS_PDEN;
  float* pnum = ws + WS_PNUM2;

  k_pool<<<512, 256, 0, stream>>>(x, pool, mk);
  k_gca_wt<<<146, 256, 0, stream>>>(pool, gq_w, gq_b, gk_w, gk_b, gv_w, gv_b,
                                    g_gamma, g, conv_w, wtb);
  k_qk<<<512, 256, 0, stream>>>(x, nl_q_w, nl_q_b, nl_k_w, nl_k_b, qk, mk);
  k_v<<<512, 256, 0, stream>>>(x, nl_v_w, nl_v_b, vt);
  if (ws_size >= WS_SPLIT2_BYTES){
    k_flash<1><<<1024, 256, 0, stream>>>(x, qk, mk, vt, g, nl_gamma, ctx2b, pnum, pden);
    k_combine<2><<<512, 256, 0, stream>>>(pnum, pden, x, g, nl_gamma, ctx2b);
  } else {
    k_flash<0><<<512, 256, 0, stream>>>(x, qk, mk, vt, g, nl_gamma, ctx2b, pnum, pden);
  }
  k_conv<<<512, 256, 0, stream>>>(ctx2b, wtb, conv_b, bn_w, bn_b, bn_mean,
                                  bn_var, gamma, x, out);
}

// Round 20
// 123.562 us; speedup vs baseline: 1.2095x; 1.0256x over previous
//
#include <hip/hip_runtime.h>
#include <hip/hip_bf16.h>

typedef float f32x4 __attribute__((ext_vector_type(4)));
typedef short short8 __attribute__((ext_vector_type(8)));
typedef unsigned int u32;

#define LOG2E 1.44269504088896f

// ---------------- ws layout (float offsets) ----------------
#define WS_POOL 0
#define WS_G    1024
#define WS_QK   2048
#define WS_MK   133120
#define WS_VT   134144
#define WS_WT   1182720            // bf16 [tap][co][ci] 36864 elems
#define WS_CTX  1219584            // bf16 [b][c][y][x] 2097152 elems
#define WS_PDEN 3316736            // f32 [1024 tiles][64]
#define WS_PNUM2 3382272           // f32 [1024 tiles][4096]
#define WS_SPLIT2_BYTES ((size_t)(WS_PNUM2 + 4194304) * 4)

// ---------------- 1. adaptive max pool 128x128 -> 2x2 (+ mk zero-init) ----
__global__ void k_pool(const float* __restrict__ x, float* __restrict__ pool,
                       u32* __restrict__ mk){
  if (blockIdx.x == 0 && threadIdx.x < 16) mk[threadIdx.x] = 0u;
  int bid = blockIdx.x;            // ((b*64+c)*4 + t)
  int t4 = bid & 3; int c = (bid >> 2) & 63; int b = bid >> 8;
  int i = t4 >> 1, j = t4 & 1;
  const float* base = x + (((b*64 + c)*128) + i*64)*128 + j*64;
  int tid = threadIdx.x;
  float m = -3.402823466e38f;
  for (int k = tid; k < 4096; k += 256){
    int r = k >> 6, cc = k & 63;
    m = fmaxf(m, base[r*128 + cc]);
  }
  __shared__ float red[256];
  red[tid] = m; __syncthreads();
  for (int s = 128; s > 0; s >>= 1){
    if (tid < s) red[tid] = fmaxf(red[tid], red[tid + s]);
    __syncthreads();
  }
  if (tid == 0) pool[bid] = red[0];
}

// ---------------- 2. tiny non-local on pooled 2x2  +  conv-weight transform
__global__ void k_gca_wt(const float* __restrict__ pool,
                      const float* qw, const float* qb,
                      const float* kw, const float* kb,
                      const float* vw, const float* vb,
                      const float* gamma, float* __restrict__ g,
                      const float* __restrict__ w, __hip_bfloat16* __restrict__ wtb){
  if (blockIdx.x >= 2){
    int idx = (int)(blockIdx.x - 2)*256 + threadIdx.x;   // 36864 total
    if (idx < 36864){
      int ci = idx & 63; int t2 = idx >> 6; int co = t2 & 63; int tap = t2 >> 6;
      wtb[idx] = __float2bfloat16(w[(co*64 + ci)*9 + tap]);
    }
    return;
  }
  int b = blockIdx.x; int c = threadIdx.x;
  __shared__ float P[64][4];
  if (c < 64){
    #pragma unroll
    for (int t = 0; t < 4; t++) P[c][t] = pool[(b*64 + c)*4 + t];
  }
  __syncthreads();
  if (c >= 64) return;
  float q[2][4], kk[2][4];
  #pragma unroll
  for (int i = 0; i < 2; i++)
    #pragma unroll
    for (int n = 0; n < 4; n++){
      float a = qb[i], e = kb[i];
      for (int ci = 0; ci < 64; ci++){
        a += qw[i*64 + ci] * P[ci][n];
        e += kw[i*64 + ci] * P[ci][n];
      }
      q[i][n] = a; kk[i][n] = e;
    }
  float att[4][4];
  #pragma unroll
  for (int n = 0; n < 4; n++){
    float mx = -3.402823466e38f;
    #pragma unroll
    for (int m2 = 0; m2 < 4; m2++){
      att[n][m2] = q[0][n]*kk[0][m2] + q[1][n]*kk[1][m2];
      mx = fmaxf(mx, att[n][m2]);
    }
    float s = 0.f;
    #pragma unroll
    for (int m2 = 0; m2 < 4; m2++){ att[n][m2] = __expf(att[n][m2] - mx); s += att[n][m2]; }
    float inv = 1.f / s;
    #pragma unroll
    for (int m2 = 0; m2 < 4; m2++) att[n][m2] *= inv;
  }
  float v[4];
  #pragma unroll
  for (int m2 = 0; m2 < 4; m2++){
    float a = vb[c];
    for (int ci = 0; ci < 64; ci++) a += vw[c*64 + ci] * P[ci][m2];
    v[m2] = a;
  }
  float gm = gamma[0];
  #pragma unroll
  for (int n = 0; n < 4; n++){
    float o = 0.f;
    #pragma unroll
    for (int m2 = 0; m2 < 4; m2++) o += v[m2] * att[n][m2];
    g[(b*64 + c)*4 + n] = gm*o + P[c][n];
  }
}

// ---------------- 3. q,k,V producer: LDS-staged x tile (R14-proven) -------
__global__ __launch_bounds__(256, 8)
void k_qkv(const float* __restrict__ x,
           const float* __restrict__ qw, const float* __restrict__ qb,
           const float* __restrict__ kw, const float* __restrict__ kb,
           const float* __restrict__ vw, const float* __restrict__ vb,
           float* __restrict__ qk, __hip_bfloat16* __restrict__ vt,
           u32* __restrict__ mk){
  int mt = blockIdx.x & 63; int combo = blockIdx.x >> 6;
  int b = combo >> 2; int si = (combo >> 1) & 1; int sj = combo & 1;
  int tid = threadIdx.x; int w = tid >> 6; int m = tid & 63;

  __shared__ __attribute__((aligned(16))) float x_lds[64][64];

  const float* xbase = x + (b*64)*16384 + (si*64 + mt)*128 + sj*64;
  #pragma unroll
  for (int k = 0; k < 4; k++){
    int idx = k*256 + tid;
    int row = idx >> 4, c4 = idx & 15;
    f32x4 v = *(const f32x4*)(xbase + row*16384 + c4*4);
    *(f32x4*)(&x_lds[row][c4*4]) = v;
  }
  __syncthreads();

  const float* wsel = (w == 0) ? qw : (w == 1) ? (qw + 64) : (w == 2) ? kw : (kw + 64);
  float bias = (w == 0) ? qb[0] : (w == 1) ? qb[1] : (w == 2) ? kb[0] : kb[1];
  float qkv_ = bias;
  for (int ci = 0; ci < 64; ci++) qkv_ = fmaf(wsel[ci], x_lds[ci][m], qkv_);
  float scale = (w < 2) ? LOG2E : 1.0f;
  qk[combo*16384 + w*4096 + mt*64 + m] = qkv_ * scale;
  if (w >= 2){
    float av = fabsf(qkv_);
    #pragma unroll
    for (int s = 1; s < 64; s <<= 1) av = fmaxf(av, __shfl_xor(av, s, 64));
    if (m == 0) atomicMax(&mk[combo*2 + (w - 2)], __float_as_uint(av));
  }

  float acc[16];
  #pragma unroll
  for (int k = 0; k < 16; k++) acc[k] = vb[w*16 + k];
  for (int ci = 0; ci < 64; ci++){
    float xv = x_lds[ci][m];
    const float* wr = vw + ci;
    #pragma unroll
    for (int k = 0; k < 16; k++)
      acc[k] = fmaf(wr[(w*16 + k)*64], xv, acc[k]);
  }
  __hip_bfloat16* vtc = vt + combo*64*4096 + mt*64 + m;
  #pragma unroll
  for (int k = 0; k < 16; k++)
    vtc[(w*16 + k)*4096] = __float2bfloat16(acc[k]);
}

// ============ half-split flash (R14-proven: K in LDS, cvt_pk, exp2-direct) =
#define EXP2R(x) __builtin_amdgcn_exp2f(x)

#define STAGE(BUFI, MT) do { \
    const __hip_bfloat16* srcb_ = vtc + (MT)*128; \
    _Pragma("unroll") \
    for (int i_ = 0; i_ < 4; i_++){ \
      __builtin_amdgcn_global_load_lds( \
        (const __attribute__((address_space(1))) u32*)(srcb_ + soff[i_]), \
        (__attribute__((address_space(3))) u32*)(&vbuf[BUFI][wave*1024 + i_*4096]), \
        16, 0, 0); \
    } \
    if (wave == 0){ \
      __builtin_amdgcn_global_load_lds( \
        (const __attribute__((address_space(1))) u32*)(qkc + 8192 + (MT)*128 + koff), \
        (__attribute__((address_space(3))) u32*)(&kbuf[BUFI][0]), \
        16, 0, 0); \
    } \
  } while(0)

#define CITER(BUFI, MT, DOSTAGE) do { \
    __syncthreads(); \
    if (DOSTAGE) STAGE(1-(BUFI), (MT)+1); \
    const unsigned char* kp_ = &kbuf[BUFI][0]; \
    _Pragma("unroll") \
    for (int ks_ = 0; ks_ < 4; ks_++){ \
      f32x4 ka = *(const f32x4*)(kp_ + mg32 + ks_*128); \
      f32x4 kb = *(const f32x4*)(kp_ + mg32 + ks_*128 + 16); \
      f32x4 kc = *(const f32x4*)(kp_ + 512 + mg32 + ks_*128); \
      f32x4 kd = *(const f32x4*)(kp_ + 512 + mg32 + ks_*128 + 16); \
      float e0_ = EXP2R(fmaf(q1, ka[0], fmaf(q2, kc[0], nbound))); \
      float e1_ = EXP2R(fmaf(q1, ka[1], fmaf(q2, kc[1], nbound))); \
      float e2_ = EXP2R(fmaf(q1, ka[2], fmaf(q2, kc[2], nbound))); \
      float e3_ = EXP2R(fmaf(q1, ka[3], fmaf(q2, kc[3], nbound))); \
      float f0_ = EXP2R(fmaf(q1, kb[0], fmaf(q2, kd[0], nbound))); \
      float f1_ = EXP2R(fmaf(q1, kb[1], fmaf(q2, kd[1], nbound))); \
      float f2_ = EXP2R(fmaf(q1, kb[2], fmaf(q2, kd[2], nbound))); \
      float f3_ = EXP2R(fmaf(q1, kb[3], fmaf(q2, kd[3], nbound))); \
      den += ((e0_+e1_) + (e2_+e3_)) + ((f0_+f1_) + (f2_+f3_)); \
      union { u32 w[4]; short8 v; } afu_; \
      asm("v_cvt_pk_bf16_f32 %0, %1, %2" : "=v"(afu_.w[0]) : "v"(e0_), "v"(e1_)); \
      asm("v_cvt_pk_bf16_f32 %0, %1, %2" : "=v"(afu_.w[1]) : "v"(e2_), "v"(e3_)); \
      asm("v_cvt_pk_bf16_f32 %0, %1, %2" : "=v"(afu_.w[2]) : "v"(f0_), "v"(f1_)); \
      asm("v_cvt_pk_bf16_f32 %0, %1, %2" : "=v"(afu_.w[3]) : "v"(f2_), "v"(f3_)); \
      short8 af = afu_.v; \
      _Pragma("unroll") \
      for (int cg_ = 0; cg_ < 4; cg_++){ \
        short8 bf = *(const short8*)(&vbuf[BUFI][ra[ks_*4+cg_]]); \
        acc[cg_] = __builtin_amdgcn_mfma_f32_16x16x32_bf16(af, bf, acc[cg_], 0, 0, 0); \
      } \
    } \
  } while(0)

template<int SPLIT>
__global__ __launch_bounds__(256, 4)
void k_flash(const float* __restrict__ x, const float* __restrict__ qk,
             const u32* __restrict__ mk, const __hip_bfloat16* __restrict__ vt,
             const float* __restrict__ g, const float* __restrict__ nl_gamma_p,
             __hip_bfloat16* __restrict__ ctx2b, float* __restrict__ pnum,
             float* __restrict__ pden){
  int combo, ntile, half;
  if (SPLIT){
    combo = blockIdx.x >> 7; int r = blockIdx.x & 127;
    ntile = r >> 1; half = r & 1;
  } else {
    combo = blockIdx.x >> 6; ntile = blockIdx.x & 63; half = 0;
  }
  int b = combo >> 2, si = (combo >> 1) & 1, sj = combo & 1;
  int tid = threadIdx.x; int wave = tid >> 6; int lane = tid & 63;
  int l15 = lane & 15, mg = lane >> 4;

  __shared__ __attribute__((aligned(16))) unsigned char vbuf[2][16384];
  __shared__ __attribute__((aligned(16))) unsigned char kbuf[2][1024];

  const float* qkc = qk + combo*16384;
  int n = ntile*64 + wave*16 + l15;
  float q1 = qkc[n], q2 = qkc[4096 + n];
  float nbound = -(fabsf(q1)*__uint_as_float(mk[combo*2]) +
                   fabsf(q2)*__uint_as_float(mk[combo*2+1]));

  f32x4 acc[4];
  #pragma unroll
  for (int cg = 0; cg < 4; cg++) acc[cg] = (f32x4){0.f,0.f,0.f,0.f};
  float den = 0.f;

  const __hip_bfloat16* vtc = vt + combo*64*4096;

  int ra[16];
  #pragma unroll
  for (int ks = 0; ks < 4; ks++)
    #pragma unroll
    for (int cg = 0; cg < 4; cg++){
      int c = l15 + (cg << 4);
      ra[ks*4+cg] = (c << 8) + ((((ks<<2)+mg) ^ (c & 7)) << 4);
    }
  int soff[4];
  #pragma unroll
  for (int i = 0; i < 4; i++){
    int gi = i*256 + tid;
    int row = gi >> 4, gg = gi & 15;
    int sg = gg ^ (row & 7);
    soff[i] = row*4096 + sg*8;
  }
  int koff = (lane & 31)*4 + (lane >> 5)*4096;
  int mg32 = mg*32;

  const int MT0 = SPLIT ? half*16 : 0;
  const int NP  = SPLIT ? 8 : 16;

  STAGE(0, MT0);
  #pragma unroll 1
  for (int mt2 = 0; mt2 < NP; mt2++){
    CITER(0, MT0 + mt2*2,     1);
    CITER(1, MT0 + mt2*2 + 1, (mt2 < NP-1));
  }

  den += __shfl_xor(den, 16, 64);
  den += __shfl_xor(den, 32, 64);

  if (SPLIT){
    int tile = (half*8 + combo)*64 + ntile;
    #pragma unroll
    for (int cg = 0; cg < 4; cg++){
      int c = l15 + (cg << 4);
      float* pn = pnum + tile*4096 + c*64 + wave*16 + mg*4;
      *(f32x4*)pn = acc[cg];
    }
    if (mg == 0) pden[tile*64 + wave*16 + l15] = den;
  } else {
    float inv = 1.f / den;
    float invj[4];
    #pragma unroll
    for (int j = 0; j < 4; j++) invj[j] = __shfl(inv, mg*4 + j, 64);

    float nlg = nl_gamma_p[0];
    int Y  = si*64 + ntile;
    int X0 = sj*64 + wave*16 + mg*4;
    float fy = Y * (1.f/127.f);
    #pragma unroll
    for (int cg = 0; cg < 4; cg++){
      int c = l15 + (cg << 4);
      f32x4 gv = *(const f32x4*)(g + (b*64 + c)*4);
      float top_l = gv[0] + fy*(gv[2] - gv[0]);
      float top_r = gv[1] + fy*(gv[3] - gv[1]);
      const float* xrow = x + ((b*64 + c)*128 + Y)*128 + X0;
      f32x4 xv = *(const f32x4*)xrow;
      f32x4 o;
      #pragma unroll
      for (int j = 0; j < 4; j++){
        float val = acc[cg][j] * invj[j];
        float ctx = fmaf(nlg, val, xv[j]);
        float fx = (X0 + j) * (1.f/127.f);
        float gg = top_l + fx*(top_r - top_l);
        float gate = 1.f / (1.f + __expf(-gg));
        o[j] = ctx * gate;
      }
      u32 pk0, pk1;
      asm("v_cvt_pk_bf16_f32 %0, %1, %2" : "=v"(pk0) : "v"(o[0]), "v"(o[1]));
      asm("v_cvt_pk_bf16_f32 %0, %1, %2" : "=v"(pk1) : "v"(o[2]), "v"(o[3]));
      u32* dst = (u32*)(ctx2b + (b*64 + c)*16384 + Y*128 + X0);
      dst[0] = pk0; dst[1] = pk1;
    }
  }
}

// ---------------- 4b. combine halves + normalize + gate (bf16 out) --------
template<int S>
__global__ __launch_bounds__(256)
void k_combine(const float* __restrict__ pnum, const float* __restrict__ pden,
               const float* __restrict__ x, const float* __restrict__ g,
               const float* __restrict__ nl_gamma_p, __hip_bfloat16* __restrict__ ctx2b){
  int bid = blockIdx.x; int combo = bid >> 6; int nt = bid & 63;
  int b = combo >> 2, si = (combo >> 1) & 1, sj = combo & 1;
  int tid = threadIdx.x; int c = tid >> 2; int nq = tid & 3;
  int tile0 = combo*64 + nt;
  float inv[16];
  #pragma unroll
  for (int q = 0; q < 4; q++){
    f32x4 dsum = (f32x4){0.f,0.f,0.f,0.f};
    #pragma unroll
    for (int p = 0; p < S; p++){
      f32x4 d = *(const f32x4*)(pden + (tile0 + p*512)*64 + nq*16 + q*4);
      #pragma unroll
      for (int j = 0; j < 4; j++) dsum[j] += d[j];
    }
    #pragma unroll
    for (int j = 0; j < 4; j++) inv[q*4+j] = 1.f / fmaxf(dsum[j], 1e-30f);
  }
  int Y = si*64 + nt; int X0 = sj*64 + nq*16;
  float fy = Y * (1.f/127.f);
  f32x4 gv = *(const f32x4*)(g + (b*64 + c)*4);
  float top_l = gv[0] + fy*(gv[2] - gv[0]);
  float top_r = gv[1] + fy*(gv[3] - gv[1]);
  float nlg = nl_gamma_p[0];
  const float* xrow = x + ((b*64 + c)*128 + Y)*128 + X0;
  __hip_bfloat16* orow = ctx2b + ((b*64 + c)*128 + Y)*128 + X0;
  #pragma unroll
  for (int q = 0; q < 4; q++){
    f32x4 xv = *(const f32x4*)(xrow + q*4);
    f32x4 nsum = (f32x4){0.f,0.f,0.f,0.f};
    #pragma unroll
    for (int p = 0; p < S; p++){
      f32x4 nv = *(const f32x4*)(pnum + (size_t)(tile0 + p*512)*4096 + c*64 + nq*16 + q*4);
      #pragma unroll
      for (int j = 0; j < 4; j++) nsum[j] += nv[j];
    }
    f32x4 o;
    #pragma unroll
    for (int j = 0; j < 4; j++){
      float val = nsum[j] * inv[q*4 + j];
      float ctx = fmaf(nlg, val, xv[j]);
      float fx = (X0 + q*4 + j) * (1.f/127.f);
      float gg = top_l + fx*(top_r - top_l);
      o[j] = ctx / (1.f + __expf(-gg));
    }
    u32 pk0, pk1;
    asm("v_cvt_pk_bf16_f32 %0, %1, %2" : "=v"(pk0) : "v"(o[0]), "v"(o[1]));
    asm("v_cvt_pk_bf16_f32 %0, %1, %2" : "=v"(pk1) : "v"(o[2]), "v"(o[3]));
    u32* dst = (u32*)(orow + q*4);
    dst[0] = pk0; dst[1] = pk1;
  }
}

// ---------------- 5. MFMA 3x3 conv (9 shifted 1x1 GEMMs) + BN + relu ------
__global__ __launch_bounds__(256, 2)
void k_conv(const __hip_bfloat16* __restrict__ ctx2b,
            const __hip_bfloat16* __restrict__ wtb,
            const float* __restrict__ cb, const float* __restrict__ bnw,
            const float* __restrict__ bnb, const float* __restrict__ bnm,
            const float* __restrict__ bnv, const float* __restrict__ gp,
            const float* __restrict__ x, float* __restrict__ out){
  int xh = blockIdx.x & 1; int y = (blockIdx.x >> 1) & 127; int b = blockIdx.x >> 8;
  int xbase = xh*64;
  int tid = threadIdx.x; int w = tid >> 6; int lane = tid & 63;
  int l15 = lane & 15, mg = lane >> 4;

  __shared__ __attribute__((aligned(16))) unsigned char ldsT[25344]; // [3][66][64ci] bf16

  for (int t = tid; t < 1584; t += 256){      // 3*66*8 granules
    int r = t / 528; int rem = t - r*528; int q = rem >> 3; int gg = rem & 7;
    int gy = y + r - 1; int gx = xbase + q - 1;
    short8 val = (short8){0,0,0,0,0,0,0,0};
    if (gy >= 0 && gy < 128 && gx >= 0 && gx < 128){
      const short* src = (const short*)(ctx2b + (b*64 + gg*8)*16384 + gy*128 + gx);
      #pragma unroll
      for (int i = 0; i < 8; i++) val[i] = src[i*16384];
    }
    int gs = gg ^ (q & 7);
    *(short8*)(&ldsT[(r*66 + q)*128 + gs*16]) = val;
  }
  __syncthreads();

  f32x4 acc[4];
  #pragma unroll
  for (int p = 0; p < 4; p++) acc[p] = (f32x4){0.f,0.f,0.f,0.f};

  const short* wv = (const short*)wtb + (w*16 + l15)*64 + mg*8;
  #pragma unroll
  for (int tap = 0; tap < 9; tap++){
    const int r3 = tap / 3, dx = tap % 3;
    #pragma unroll
    for (int h = 0; h < 2; h++){
      short8 af = *(const short8*)(wv + tap*4096 + h*32);
      #pragma unroll
      for (int p = 0; p < 4; p++){
        int q = p*16 + l15 + dx;
        int gs = ((h << 2) + mg) ^ (q & 7);
        short8 bf = *(const short8*)(&ldsT[(r3*66 + q)*128 + gs*16]);
        acc[p] = __builtin_amdgcn_mfma_f32_16x16x32_bf16(af, bf, acc[p], 0, 0, 0);
      }
    }
  }

  float gam = gp[0];
  #pragma unroll
  for (int r = 0; r < 4; r++){
    int co = w*16 + mg*4 + r;
    float scale = bnw[co] * rsqrtf(bnv[co] + 1e-5f);
    float shift = bnb[co] - bnm[co]*scale;
    float cbv = cb[co];
    const float* xrow = x + (b*64 + co)*16384 + y*128 + xbase;
    float* orow = out + (b*64 + co)*16384 + y*128 + xbase;
    #pragma unroll
    for (int p = 0; p < 4; p++){
      int px = p*16 + l15;
      float t = (acc[p][r] + cbv)*scale + shift;
      orow[px] = fmaxf(fmaf(gam, t, xrow[px]), 0.f);
    }
  }
}

extern "C" void kernel_launch(void* const* d_in, const int* in_sizes, int n_in,
                              void* d_out, int out_size, void* d_ws, size_t ws_size,
                              hipStream_t stream) {
  const float* x        = (const float*)d_in[0];
  const float* nl_q_w   = (const float*)d_in[1];
  const float* nl_q_b   = (const float*)d_in[2];
  const float* nl_k_w   = (const float*)d_in[3];
  const float* nl_k_b   = (const float*)d_in[4];
  const float* nl_v_w   = (const float*)d_in[5];
  const float* nl_v_b   = (const float*)d_in[6];
  const float* nl_gamma = (const float*)d_in[7];
  const float* gq_w     = (const float*)d_in[8];
  const float* gq_b     = (const float*)d_in[9];
  const float* gk_w     = (const float*)d_in[10];
  const float* gk_b     = (const float*)d_in[11];
  const float* gv_w     = (const float*)d_in[12];
  const float* gv_b     = (const float*)d_in[13];
  const float* g_gamma  = (const float*)d_in[14];
  const float* conv_w   = (const float*)d_in[15];
  const float* conv_b   = (const float*)d_in[16];
  const float* bn_w     = (const float*)d_in[17];
  const float* bn_b     = (const float*)d_in[18];
  const float* bn_mean  = (const float*)d_in[19];
  const float* bn_var   = (const float*)d_in[20];
  const float* gamma    = (const float*)d_in[21];
  float* out = (float*)d_out;

  float* ws = (float*)d_ws;
  float* pool = ws + WS_POOL;
  float* g    = ws + WS_G;
  float* qk   = ws + WS_QK;
  u32*   mk   = (u32*)(ws + WS_MK);
  __hip_bfloat16* vt   = (__hip_bfloat16*)(ws + WS_VT);
  __hip_bfloat16* wtb  = (__hip_bfloat16*)(ws + WS_WT);
  __hip_bfloat16* ctx2b= (__hip_bfloat16*)(ws + WS_CTX);
  float* pden = ws + WS_PDEN;
  float* pnum = ws + WS_PNUM2;

  k_pool<<<512, 256, 0, stream>>>(x, pool, mk);
  k_gca_wt<<<146, 256, 0, stream>>>(pool, gq_w, gq_b, gk_w, gk_b, gv_w, gv_b,
                                    g_gamma, g, conv_w, wtb);
  k_qkv<<<512, 256, 0, stream>>>(x, nl_q_w, nl_q_b, nl_k_w, nl_k_b,
                                 nl_v_w, nl_v_b, qk, vt, mk);
  if (ws_size >= WS_SPLIT2_BYTES){
    k_flash<1><<<1024, 256, 0, stream>>>(x, qk, mk, vt, g, nl_gamma, ctx2b, pnum, pden);
    k_combine<2><<<512, 256, 0, stream>>>(pnum, pden, x, g, nl_gamma, ctx2b);
  } else {
    k_flash<0><<<512, 256, 0, stream>>>(x, qk, mk, vt, g, nl_gamma, ctx2b, pnum, pden);
  }
  k_conv<<<512, 256, 0, stream>>>(ctx2b, wtb, conv_b, bn_w, bn_b, bn_mean,
                                  bn_var, gamma, x, out);
}

// Round 21
// 123.135 us; speedup vs baseline: 1.2137x; 1.0035x over previous
//
#include <hip/hip_runtime.h>
#include <hip/hip_bf16.h>

typedef float f32x4 __attribute__((ext_vector_type(4)));
typedef short short8 __attribute__((ext_vector_type(8)));
typedef unsigned int u32;

#define LOG2E 1.44269504088896f

// ---------------- ws layout (float offsets) ----------------
#define WS_POOL 0
#define WS_G    1024
#define WS_QK   2048
#define WS_MK   133120
#define WS_VT   134144
#define WS_WT   1182720            // bf16 [tap][co][ci] 36864 elems
#define WS_CTX  1219584            // bf16 [b][c][y][x] 2097152 elems
#define WS_PDEN 3316736            // f32 [1024 tiles][64]
#define WS_PNUM2 3382272           // f32 [1024 tiles][4096]
#define WS_SPLIT2_BYTES ((size_t)(WS_PNUM2 + 4194304) * 4)

// ---------------- 1. adaptive max pool 128x128 -> 2x2 (+ mk zero-init) ----
__global__ void k_pool(const float* __restrict__ x, float* __restrict__ pool,
                       u32* __restrict__ mk){
  if (blockIdx.x == 0 && threadIdx.x < 16) mk[threadIdx.x] = 0u;
  int bid = blockIdx.x;            // ((b*64+c)*4 + t)
  int t4 = bid & 3; int c = (bid >> 2) & 63; int b = bid >> 8;
  int i = t4 >> 1, j = t4 & 1;
  const float* base = x + (((b*64 + c)*128) + i*64)*128 + j*64;
  int tid = threadIdx.x;
  float m = -3.402823466e38f;
  for (int k = tid; k < 4096; k += 256){
    int r = k >> 6, cc = k & 63;
    m = fmaxf(m, base[r*128 + cc]);
  }
  __shared__ float red[256];
  red[tid] = m; __syncthreads();
  for (int s = 128; s > 0; s >>= 1){
    if (tid < s) red[tid] = fmaxf(red[tid], red[tid + s]);
    __syncthreads();
  }
  if (tid == 0) pool[bid] = red[0];
}

// ---------------- 2. tiny non-local on pooled 2x2  +  conv-weight transform
__global__ void k_gca_wt(const float* __restrict__ pool,
                      const float* qw, const float* qb,
                      const float* kw, const float* kb,
                      const float* vw, const float* vb,
                      const float* gamma, float* __restrict__ g,
                      const float* __restrict__ w, __hip_bfloat16* __restrict__ wtb){
  if (blockIdx.x >= 2){
    int idx = (int)(blockIdx.x - 2)*256 + threadIdx.x;   // 36864 total
    if (idx < 36864){
      int ci = idx & 63; int t2 = idx >> 6; int co = t2 & 63; int tap = t2 >> 6;
      wtb[idx] = __float2bfloat16(w[(co*64 + ci)*9 + tap]);
    }
    return;
  }
  int b = blockIdx.x; int c = threadIdx.x;
  __shared__ float P[64][4];
  if (c < 64){
    #pragma unroll
    for (int t = 0; t < 4; t++) P[c][t] = pool[(b*64 + c)*4 + t];
  }
  __syncthreads();
  if (c >= 64) return;
  float q[2][4], kk[2][4];
  #pragma unroll
  for (int i = 0; i < 2; i++)
    #pragma unroll
    for (int n = 0; n < 4; n++){
      float a = qb[i], e = kb[i];
      for (int ci = 0; ci < 64; ci++){
        a += qw[i*64 + ci] * P[ci][n];
        e += kw[i*64 + ci] * P[ci][n];
      }
      q[i][n] = a; kk[i][n] = e;
    }
  float att[4][4];
  #pragma unroll
  for (int n = 0; n < 4; n++){
    float mx = -3.402823466e38f;
    #pragma unroll
    for (int m2 = 0; m2 < 4; m2++){
      att[n][m2] = q[0][n]*kk[0][m2] + q[1][n]*kk[1][m2];
      mx = fmaxf(mx, att[n][m2]);
    }
    float s = 0.f;
    #pragma unroll
    for (int m2 = 0; m2 < 4; m2++){ att[n][m2] = __expf(att[n][m2] - mx); s += att[n][m2]; }
    float inv = 1.f / s;
    #pragma unroll
    for (int m2 = 0; m2 < 4; m2++) att[n][m2] *= inv;
  }
  float v[4];
  #pragma unroll
  for (int m2 = 0; m2 < 4; m2++){
    float a = vb[c];
    for (int ci = 0; ci < 64; ci++) a += vw[c*64 + ci] * P[ci][m2];
    v[m2] = a;
  }
  float gm = gamma[0];
  #pragma unroll
  for (int n = 0; n < 4; n++){
    float o = 0.f;
    #pragma unroll
    for (int m2 = 0; m2 < 4; m2++) o += v[m2] * att[n][m2];
    g[(b*64 + c)*4 + n] = gm*o + P[c][n];
  }
}

// ---------------- 3. q,k,V producer: async global_load_lds x staging ------
__global__ __launch_bounds__(256, 8)
void k_qkv(const float* __restrict__ x,
           const float* __restrict__ qw, const float* __restrict__ qb,
           const float* __restrict__ kw, const float* __restrict__ kb,
           const float* __restrict__ vw, const float* __restrict__ vb,
           float* __restrict__ qk, __hip_bfloat16* __restrict__ vt,
           u32* __restrict__ mk){
  int mt = blockIdx.x & 63; int combo = blockIdx.x >> 6;
  int b = combo >> 2; int si = (combo >> 1) & 1; int sj = combo & 1;
  int tid = threadIdx.x; int w = tid >> 6; int m = tid & 63;

  __shared__ __attribute__((aligned(16))) float x_lds[64][64];

  // async DMA staging: dest = wave-uniform base + lane*16 (HW contract);
  // identical byte layout to the previous reg-round-trip staging.
  const float* xbase = x + (b*64)*16384 + (si*64 + mt)*128 + sj*64;
  #pragma unroll
  for (int k = 0; k < 4; k++){
    int idx = k*256 + tid;
    int row = idx >> 4, c4 = idx & 15;
    __builtin_amdgcn_global_load_lds(
      (const __attribute__((address_space(1))) u32*)(xbase + row*16384 + c4*4),
      (__attribute__((address_space(3))) u32*)(&x_lds[0][0] + k*1024 + w*256),
      16, 0, 0);
  }
  __syncthreads();

  const float* wsel = (w == 0) ? qw : (w == 1) ? (qw + 64) : (w == 2) ? kw : (kw + 64);
  float bias = (w == 0) ? qb[0] : (w == 1) ? qb[1] : (w == 2) ? kb[0] : kb[1];
  float qkv_ = bias;
  for (int ci = 0; ci < 64; ci++) qkv_ = fmaf(wsel[ci], x_lds[ci][m], qkv_);
  float scale = (w < 2) ? LOG2E : 1.0f;
  qk[combo*16384 + w*4096 + mt*64 + m] = qkv_ * scale;
  if (w >= 2){
    float av = fabsf(qkv_);
    #pragma unroll
    for (int s = 1; s < 64; s <<= 1) av = fmaxf(av, __shfl_xor(av, s, 64));
    if (m == 0) atomicMax(&mk[combo*2 + (w - 2)], __float_as_uint(av));
  }

  float acc[16];
  #pragma unroll
  for (int k = 0; k < 16; k++) acc[k] = vb[w*16 + k];
  for (int ci = 0; ci < 64; ci++){
    float xv = x_lds[ci][m];
    const float* wr = vw + ci;
    #pragma unroll
    for (int k = 0; k < 16; k++)
      acc[k] = fmaf(wr[(w*16 + k)*64], xv, acc[k]);
  }
  __hip_bfloat16* vtc = vt + combo*64*4096 + mt*64 + m;
  #pragma unroll
  for (int k = 0; k < 16; k++)
    vtc[(w*16 + k)*4096] = __float2bfloat16(acc[k]);
}

// ============ half-split flash (R14-proven: K in LDS, cvt_pk, exp2-direct) =
#define EXP2R(x) __builtin_amdgcn_exp2f(x)

#define STAGE(BUFI, MT) do { \
    const __hip_bfloat16* srcb_ = vtc + (MT)*128; \
    _Pragma("unroll") \
    for (int i_ = 0; i_ < 4; i_++){ \
      __builtin_amdgcn_global_load_lds( \
        (const __attribute__((address_space(1))) u32*)(srcb_ + soff[i_]), \
        (__attribute__((address_space(3))) u32*)(&vbuf[BUFI][wave*1024 + i_*4096]), \
        16, 0, 0); \
    } \
    if (wave == 0){ \
      __builtin_amdgcn_global_load_lds( \
        (const __attribute__((address_space(1))) u32*)(qkc + 8192 + (MT)*128 + koff), \
        (__attribute__((address_space(3))) u32*)(&kbuf[BUFI][0]), \
        16, 0, 0); \
    } \
  } while(0)

#define CITER(BUFI, MT, DOSTAGE) do { \
    __syncthreads(); \
    if (DOSTAGE) STAGE(1-(BUFI), (MT)+1); \
    const unsigned char* kp_ = &kbuf[BUFI][0]; \
    _Pragma("unroll") \
    for (int ks_ = 0; ks_ < 4; ks_++){ \
      f32x4 ka = *(const f32x4*)(kp_ + mg32 + ks_*128); \
      f32x4 kb = *(const f32x4*)(kp_ + mg32 + ks_*128 + 16); \
      f32x4 kc = *(const f32x4*)(kp_ + 512 + mg32 + ks_*128); \
      f32x4 kd = *(const f32x4*)(kp_ + 512 + mg32 + ks_*128 + 16); \
      float e0_ = EXP2R(fmaf(q1, ka[0], fmaf(q2, kc[0], nbound))); \
      float e1_ = EXP2R(fmaf(q1, ka[1], fmaf(q2, kc[1], nbound))); \
      float e2_ = EXP2R(fmaf(q1, ka[2], fmaf(q2, kc[2], nbound))); \
      float e3_ = EXP2R(fmaf(q1, ka[3], fmaf(q2, kc[3], nbound))); \
      float f0_ = EXP2R(fmaf(q1, kb[0], fmaf(q2, kd[0], nbound))); \
      float f1_ = EXP2R(fmaf(q1, kb[1], fmaf(q2, kd[1], nbound))); \
      float f2_ = EXP2R(fmaf(q1, kb[2], fmaf(q2, kd[2], nbound))); \
      float f3_ = EXP2R(fmaf(q1, kb[3], fmaf(q2, kd[3], nbound))); \
      den += ((e0_+e1_) + (e2_+e3_)) + ((f0_+f1_) + (f2_+f3_)); \
      union { u32 w[4]; short8 v; } afu_; \
      asm("v_cvt_pk_bf16_f32 %0, %1, %2" : "=v"(afu_.w[0]) : "v"(e0_), "v"(e1_)); \
      asm("v_cvt_pk_bf16_f32 %0, %1, %2" : "=v"(afu_.w[1]) : "v"(e2_), "v"(e3_)); \
      asm("v_cvt_pk_bf16_f32 %0, %1, %2" : "=v"(afu_.w[2]) : "v"(f0_), "v"(f1_)); \
      asm("v_cvt_pk_bf16_f32 %0, %1, %2" : "=v"(afu_.w[3]) : "v"(f2_), "v"(f3_)); \
      short8 af = afu_.v; \
      _Pragma("unroll") \
      for (int cg_ = 0; cg_ < 4; cg_++){ \
        short8 bf = *(const short8*)(&vbuf[BUFI][ra[ks_*4+cg_]]); \
        acc[cg_] = __builtin_amdgcn_mfma_f32_16x16x32_bf16(af, bf, acc[cg_], 0, 0, 0); \
      } \
    } \
  } while(0)

template<int SPLIT>
__global__ __launch_bounds__(256, 4)
void k_flash(const float* __restrict__ x, const float* __restrict__ qk,
             const u32* __restrict__ mk, const __hip_bfloat16* __restrict__ vt,
             const float* __restrict__ g, const float* __restrict__ nl_gamma_p,
             __hip_bfloat16* __restrict__ ctx2b, float* __restrict__ pnum,
             float* __restrict__ pden){
  int combo, ntile, half;
  if (SPLIT){
    combo = blockIdx.x >> 7; int r = blockIdx.x & 127;
    ntile = r >> 1; half = r & 1;
  } else {
    combo = blockIdx.x >> 6; ntile = blockIdx.x & 63; half = 0;
  }
  int b = combo >> 2, si = (combo >> 1) & 1, sj = combo & 1;
  int tid = threadIdx.x; int wave = tid >> 6; int lane = tid & 63;
  int l15 = lane & 15, mg = lane >> 4;

  __shared__ __attribute__((aligned(16))) unsigned char vbuf[2][16384];
  __shared__ __attribute__((aligned(16))) unsigned char kbuf[2][1024];

  const float* qkc = qk + combo*16384;
  int n = ntile*64 + wave*16 + l15;
  float q1 = qkc[n], q2 = qkc[4096 + n];
  float nbound = -(fabsf(q1)*__uint_as_float(mk[combo*2]) +
                   fabsf(q2)*__uint_as_float(mk[combo*2+1]));

  f32x4 acc[4];
  #pragma unroll
  for (int cg = 0; cg < 4; cg++) acc[cg] = (f32x4){0.f,0.f,0.f,0.f};
  float den = 0.f;

  const __hip_bfloat16* vtc = vt + combo*64*4096;

  int ra[16];
  #pragma unroll
  for (int ks = 0; ks < 4; ks++)
    #pragma unroll
    for (int cg = 0; cg < 4; cg++){
      int c = l15 + (cg << 4);
      ra[ks*4+cg] = (c << 8) + ((((ks<<2)+mg) ^ (c & 7)) << 4);
    }
  int soff[4];
  #pragma unroll
  for (int i = 0; i < 4; i++){
    int gi = i*256 + tid;
    int row = gi >> 4, gg = gi & 15;
    int sg = gg ^ (row & 7);
    soff[i] = row*4096 + sg*8;
  }
  int koff = (lane & 31)*4 + (lane >> 5)*4096;
  int mg32 = mg*32;

  const int MT0 = SPLIT ? half*16 : 0;
  const int NP  = SPLIT ? 8 : 16;

  STAGE(0, MT0);
  #pragma unroll 1
  for (int mt2 = 0; mt2 < NP; mt2++){
    CITER(0, MT0 + mt2*2,     1);
    CITER(1, MT0 + mt2*2 + 1, (mt2 < NP-1));
  }

  den += __shfl_xor(den, 16, 64);
  den += __shfl_xor(den, 32, 64);

  if (SPLIT){
    int tile = (half*8 + combo)*64 + ntile;
    #pragma unroll
    for (int cg = 0; cg < 4; cg++){
      int c = l15 + (cg << 4);
      float* pn = pnum + tile*4096 + c*64 + wave*16 + mg*4;
      *(f32x4*)pn = acc[cg];
    }
    if (mg == 0) pden[tile*64 + wave*16 + l15] = den;
  } else {
    float inv = 1.f / den;
    float invj[4];
    #pragma unroll
    for (int j = 0; j < 4; j++) invj[j] = __shfl(inv, mg*4 + j, 64);

    float nlg = nl_gamma_p[0];
    int Y  = si*64 + ntile;
    int X0 = sj*64 + wave*16 + mg*4;
    float fy = Y * (1.f/127.f);
    #pragma unroll
    for (int cg = 0; cg < 4; cg++){
      int c = l15 + (cg << 4);
      f32x4 gv = *(const f32x4*)(g + (b*64 + c)*4);
      float top_l = gv[0] + fy*(gv[2] - gv[0]);
      float top_r = gv[1] + fy*(gv[3] - gv[1]);
      const float* xrow = x + ((b*64 + c)*128 + Y)*128 + X0;
      f32x4 xv = *(const f32x4*)xrow;
      f32x4 o;
      #pragma unroll
      for (int j = 0; j < 4; j++){
        float val = acc[cg][j] * invj[j];
        float ctx = fmaf(nlg, val, xv[j]);
        float fx = (X0 + j) * (1.f/127.f);
        float gg = top_l + fx*(top_r - top_l);
        float gate = 1.f / (1.f + __expf(-gg));
        o[j] = ctx * gate;
      }
      u32 pk0, pk1;
      asm("v_cvt_pk_bf16_f32 %0, %1, %2" : "=v"(pk0) : "v"(o[0]), "v"(o[1]));
      asm("v_cvt_pk_bf16_f32 %0, %1, %2" : "=v"(pk1) : "v"(o[2]), "v"(o[3]));
      u32* dst = (u32*)(ctx2b + (b*64 + c)*16384 + Y*128 + X0);
      dst[0] = pk0; dst[1] = pk1;
    }
  }
}

// ---------------- 4b. combine halves + normalize + gate (bf16 out) --------
template<int S>
__global__ __launch_bounds__(256)
void k_combine(const float* __restrict__ pnum, const float* __restrict__ pden,
               const float* __restrict__ x, const float* __restrict__ g,
               const float* __restrict__ nl_gamma_p, __hip_bfloat16* __restrict__ ctx2b){
  int bid = blockIdx.x; int combo = bid >> 6; int nt = bid & 63;
  int b = combo >> 2, si = (combo >> 1) & 1, sj = combo & 1;
  int tid = threadIdx.x; int c = tid >> 2; int nq = tid & 3;
  int tile0 = combo*64 + nt;
  float inv[16];
  #pragma unroll
  for (int q = 0; q < 4; q++){
    f32x4 dsum = (f32x4){0.f,0.f,0.f,0.f};
    #pragma unroll
    for (int p = 0; p < S; p++){
      f32x4 d = *(const f32x4*)(pden + (tile0 + p*512)*64 + nq*16 + q*4);
      #pragma unroll
      for (int j = 0; j < 4; j++) dsum[j] += d[j];
    }
    #pragma unroll
    for (int j = 0; j < 4; j++) inv[q*4+j] = 1.f / fmaxf(dsum[j], 1e-30f);
  }
  int Y = si*64 + nt; int X0 = sj*64 + nq*16;
  float fy = Y * (1.f/127.f);
  f32x4 gv = *(const f32x4*)(g + (b*64 + c)*4);
  float top_l = gv[0] + fy*(gv[2] - gv[0]);
  float top_r = gv[1] + fy*(gv[3] - gv[1]);
  float nlg = nl_gamma_p[0];
  const float* xrow = x + ((b*64 + c)*128 + Y)*128 + X0;
  __hip_bfloat16* orow = ctx2b + ((b*64 + c)*128 + Y)*128 + X0;
  #pragma unroll
  for (int q = 0; q < 4; q++){
    f32x4 xv = *(const f32x4*)(xrow + q*4);
    f32x4 nsum = (f32x4){0.f,0.f,0.f,0.f};
    #pragma unroll
    for (int p = 0; p < S; p++){
      f32x4 nv = *(const f32x4*)(pnum + (size_t)(tile0 + p*512)*4096 + c*64 + nq*16 + q*4);
      #pragma unroll
      for (int j = 0; j < 4; j++) nsum[j] += nv[j];
    }
    f32x4 o;
    #pragma unroll
    for (int j = 0; j < 4; j++){
      float val = nsum[j] * inv[q*4 + j];
      float ctx = fmaf(nlg, val, xv[j]);
      float fx = (X0 + q*4 + j) * (1.f/127.f);
      float gg = top_l + fx*(top_r - top_l);
      o[j] = ctx / (1.f + __expf(-gg));
    }
    u32 pk0, pk1;
    asm("v_cvt_pk_bf16_f32 %0, %1, %2" : "=v"(pk0) : "v"(o[0]), "v"(o[1]));
    asm("v_cvt_pk_bf16_f32 %0, %1, %2" : "=v"(pk1) : "v"(o[2]), "v"(o[3]));
    u32* dst = (u32*)(orow + q*4);
    dst[0] = pk0; dst[1] = pk1;
  }
}

// ---------------- 5. MFMA 3x3 conv (9 shifted 1x1 GEMMs) + BN + relu ------
__global__ __launch_bounds__(256, 2)
void k_conv(const __hip_bfloat16* __restrict__ ctx2b,
            const __hip_bfloat16* __restrict__ wtb,
            const float* __restrict__ cb, const float* __restrict__ bnw,
            const float* __restrict__ bnb, const float* __restrict__ bnm,
            const float* __restrict__ bnv, const float* __restrict__ gp,
            const float* __restrict__ x, float* __restrict__ out){
  int xh = blockIdx.x & 1; int y = (blockIdx.x >> 1) & 127; int b = blockIdx.x >> 8;
  int xbase = xh*64;
  int tid = threadIdx.x; int w = tid >> 6; int lane = tid & 63;
  int l15 = lane & 15, mg = lane >> 4;

  __shared__ __attribute__((aligned(16))) unsigned char ldsT[25344]; // [3][66][64ci] bf16

  for (int t = tid; t < 1584; t += 256){      // 3*66*8 granules
    int r = t / 528; int rem = t - r*528; int q = rem >> 3; int gg = rem & 7;
    int gy = y + r - 1; int gx = xbase + q - 1;
    short8 val = (short8){0,0,0,0,0,0,0,0};
    if (gy >= 0 && gy < 128 && gx >= 0 && gx < 128){
      const short* src = (const short*)(ctx2b + (b*64 + gg*8)*16384 + gy*128 + gx);
      #pragma unroll
      for (int i = 0; i < 8; i++) val[i] = src[i*16384];
    }
    int gs = gg ^ (q & 7);
    *(short8*)(&ldsT[(r*66 + q)*128 + gs*16]) = val;
  }
  __syncthreads();

  f32x4 acc[4];
  #pragma unroll
  for (int p = 0; p < 4; p++) acc[p] = (f32x4){0.f,0.f,0.f,0.f};

  const short* wv = (const short*)wtb + (w*16 + l15)*64 + mg*8;
  #pragma unroll
  for (int tap = 0; tap < 9; tap++){
    const int r3 = tap / 3, dx = tap % 3;
    #pragma unroll
    for (int h = 0; h < 2; h++){
      short8 af = *(const short8*)(wv + tap*4096 + h*32);
      #pragma unroll
      for (int p = 0; p < 4; p++){
        int q = p*16 + l15 + dx;
        int gs = ((h << 2) + mg) ^ (q & 7);
        short8 bf = *(const short8*)(&ldsT[(r3*66 + q)*128 + gs*16]);
        acc[p] = __builtin_amdgcn_mfma_f32_16x16x32_bf16(af, bf, acc[p], 0, 0, 0);
      }
    }
  }

  float gam = gp[0];
  #pragma unroll
  for (int r = 0; r < 4; r++){
    int co = w*16 + mg*4 + r;
    float scale = bnw[co] * rsqrtf(bnv[co] + 1e-5f);
    float shift = bnb[co] - bnm[co]*scale;
    float cbv = cb[co];
    const float* xrow = x + (b*64 + co)*16384 + y*128 + xbase;
    float* orow = out + (b*64 + co)*16384 + y*128 + xbase;
    #pragma unroll
    for (int p = 0; p < 4; p++){
      int px = p*16 + l15;
      float t = (acc[p][r] + cbv)*scale + shift;
      orow[px] = fmaxf(fmaf(gam, t, xrow[px]), 0.f);
    }
  }
}

extern "C" void kernel_launch(void* const* d_in, const int* in_sizes, int n_in,
                              void* d_out, int out_size, void* d_ws, size_t ws_size,
                              hipStream_t stream) {
  const float* x        = (const float*)d_in[0];
  const float* nl_q_w   = (const float*)d_in[1];
  const float* nl_q_b   = (const float*)d_in[2];
  const float* nl_k_w   = (const float*)d_in[3];
  const float* nl_k_b   = (const float*)d_in[4];
  const float* nl_v_w   = (const float*)d_in[5];
  const float* nl_v_b   = (const float*)d_in[6];
  const float* nl_gamma = (const float*)d_in[7];
  const float* gq_w     = (const float*)d_in[8];
  const float* gq_b     = (const float*)d_in[9];
  const float* gk_w     = (const float*)d_in[10];
  const float* gk_b     = (const float*)d_in[11];
  const float* gv_w     = (const float*)d_in[12];
  const float* gv_b     = (const float*)d_in[13];
  const float* g_gamma  = (const float*)d_in[14];
  const float* conv_w   = (const float*)d_in[15];
  const float* conv_b   = (const float*)d_in[16];
  const float* bn_w     = (const float*)d_in[17];
  const float* bn_b     = (const float*)d_in[18];
  const float* bn_mean  = (const float*)d_in[19];
  const float* bn_var   = (const float*)d_in[20];
  const float* gamma    = (const float*)d_in[21];
  float* out = (float*)d_out;

  float* ws = (float*)d_ws;
  float* pool = ws + WS_POOL;
  float* g    = ws + WS_G;
  float* qk   = ws + WS_QK;
  u32*   mk   = (u32*)(ws + WS_MK);
  __hip_bfloat16* vt   = (__hip_bfloat16*)(ws + WS_VT);
  __hip_bfloat16* wtb  = (__hip_bfloat16*)(ws + WS_WT);
  __hip_bfloat16* ctx2b= (__hip_bfloat16*)(ws + WS_CTX);
  float* pden = ws + WS_PDEN;
  float* pnum = ws + WS_PNUM2;

  k_pool<<<512, 256, 0, stream>>>(x, pool, mk);
  k_gca_wt<<<146, 256, 0, stream>>>(pool, gq_w, gq_b, gk_w, gk_b, gv_w, gv_b,
                                    g_gamma, g, conv_w, wtb);
  k_qkv<<<512, 256, 0, stream>>>(x, nl_q_w, nl_q_b, nl_k_w, nl_k_b,
                                 nl_v_w, nl_v_b, qk, vt, mk);
  if (ws_size >= WS_SPLIT2_BYTES){
    k_flash<1><<<1024, 256, 0, stream>>>(x, qk, mk, vt, g, nl_gamma, ctx2b, pnum, pden);
    k_combine<2><<<512, 256, 0, stream>>>(pnum, pden, x, g, nl_gamma, ctx2b);
  } else {
    k_flash<0><<<512, 256, 0, stream>>>(x, qk, mk, vt, g, nl_gamma, ctx2b, pnum, pden);
  }
  k_conv<<<512, 256, 0, stream>>>(ctx2b, wtb, conv_b, bn_w, bn_b, bn_mean,
                                  bn_var, gamma, x, out);
}

// Round 22
// 99.780 us; speedup vs baseline: 1.4978x; 1.2341x over previous
//
#include <hip/hip_runtime.h>
#include <hip/hip_bf16.h>

typedef float f32x4 __attribute__((ext_vector_type(4)));
typedef short short8 __attribute__((ext_vector_type(8)));
typedef unsigned int u32;

#define LOG2E 1.44269504088896f

// ---------------- ws layout (float offsets) ----------------
#define WS_POOL 0
#define WS_G    1024
#define WS_QK   2048
#define WS_MK   133120
#define WS_VT   134144
#define WS_WT   1182720            // bf16 [tap][co][ci] 36864 elems
#define WS_CTX  1219584            // bf16 [b][c][y][x] 2097152 elems
#define WS_PDEN 3316736            // f32 [1024 tiles][64]
#define WS_PNUM2 3382272           // f32 [1024 tiles][4096]
#define WS_SPLIT2_BYTES ((size_t)(WS_PNUM2 + 4194304) * 4)

// ---------------- 1. adaptive max pool 128x128 -> 2x2 (+ mk zero-init) ----
__global__ void k_pool(const float* __restrict__ x, float* __restrict__ pool,
                       u32* __restrict__ mk){
  if (blockIdx.x == 0 && threadIdx.x < 16) mk[threadIdx.x] = 0u;
  int bid = blockIdx.x;            // ((b*64+c)*4 + t)
  int t4 = bid & 3; int c = (bid >> 2) & 63; int b = bid >> 8;
  int i = t4 >> 1, j = t4 & 1;
  const float* base = x + (((b*64 + c)*128) + i*64)*128 + j*64;
  int tid = threadIdx.x;
  float m = -3.402823466e38f;
  for (int k = tid; k < 4096; k += 256){
    int r = k >> 6, cc = k & 63;
    m = fmaxf(m, base[r*128 + cc]);
  }
  __shared__ float red[256];
  red[tid] = m; __syncthreads();
  for (int s = 128; s > 0; s >>= 1){
    if (tid < s) red[tid] = fmaxf(red[tid], red[tid + s]);
    __syncthreads();
  }
  if (tid == 0) pool[bid] = red[0];
}

// ---------------- 2. tiny non-local on pooled 2x2  +  conv-weight transform
__global__ void k_gca_wt(const float* __restrict__ pool,
                      const float* qw, const float* qb,
                      const float* kw, const float* kb,
                      const float* vw, const float* vb,
                      const float* gamma, float* __restrict__ g,
                      const float* __restrict__ w, __hip_bfloat16* __restrict__ wtb){
  if (blockIdx.x >= 2){
    int idx = (int)(blockIdx.x - 2)*256 + threadIdx.x;   // 36864 total
    if (idx < 36864){
      int ci = idx & 63; int t2 = idx >> 6; int co = t2 & 63; int tap = t2 >> 6;
      wtb[idx] = __float2bfloat16(w[(co*64 + ci)*9 + tap]);
    }
    return;
  }
  int b = blockIdx.x; int c = threadIdx.x;
  __shared__ float P[64][4];
  if (c < 64){
    #pragma unroll
    for (int t = 0; t < 4; t++) P[c][t] = pool[(b*64 + c)*4 + t];
  }
  __syncthreads();
  if (c >= 64) return;
  float q[2][4], kk[2][4];
  #pragma unroll
  for (int i = 0; i < 2; i++)
    #pragma unroll
    for (int n = 0; n < 4; n++){
      float a = qb[i], e = kb[i];
      for (int ci = 0; ci < 64; ci++){
        a += qw[i*64 + ci] * P[ci][n];
        e += kw[i*64 + ci] * P[ci][n];
      }
      q[i][n] = a; kk[i][n] = e;
    }
  float att[4][4];
  #pragma unroll
  for (int n = 0; n < 4; n++){
    float mx = -3.402823466e38f;
    #pragma unroll
    for (int m2 = 0; m2 < 4; m2++){
      att[n][m2] = q[0][n]*kk[0][m2] + q[1][n]*kk[1][m2];
      mx = fmaxf(mx, att[n][m2]);
    }
    float s = 0.f;
    #pragma unroll
    for (int m2 = 0; m2 < 4; m2++){ att[n][m2] = __expf(att[n][m2] - mx); s += att[n][m2]; }
    float inv = 1.f / s;
    #pragma unroll
    for (int m2 = 0; m2 < 4; m2++) att[n][m2] *= inv;
  }
  float v[4];
  #pragma unroll
  for (int m2 = 0; m2 < 4; m2++){
    float a = vb[c];
    for (int ci = 0; ci < 64; ci++) a += vw[c*64 + ci] * P[ci][m2];
    v[m2] = a;
  }
  float gm = gamma[0];
  #pragma unroll
  for (int n = 0; n < 4; n++){
    float o = 0.f;
    #pragma unroll
    for (int m2 = 0; m2 < 4; m2++) o += v[m2] * att[n][m2];
    g[(b*64 + c)*4 + n] = gm*o + P[c][n];
  }
}

// ---------------- 3. q,k,V producer: async x staging + vw in LDS ----------
__global__ __launch_bounds__(256, 8)
void k_qkv(const float* __restrict__ x,
           const float* __restrict__ qw, const float* __restrict__ qb,
           const float* __restrict__ kw, const float* __restrict__ kb,
           const float* __restrict__ vw, const float* __restrict__ vb,
           float* __restrict__ qk, __hip_bfloat16* __restrict__ vt,
           u32* __restrict__ mk){
  int mt = blockIdx.x & 63; int combo = blockIdx.x >> 6;
  int b = combo >> 2; int si = (combo >> 1) & 1; int sj = combo & 1;
  int tid = threadIdx.x; int w = tid >> 6; int m = tid & 63;

  __shared__ __attribute__((aligned(16))) float x_lds[64][64];
  __shared__ __attribute__((aligned(16))) float vw_lds[4096];   // [co][ci]

  // async DMA staging of x tile (R21-proven layout)
  const float* xbase = x + (b*64)*16384 + (si*64 + mt)*128 + sj*64;
  #pragma unroll
  for (int k = 0; k < 4; k++){
    int idx = k*256 + tid;
    int row = idx >> 4, c4 = idx & 15;
    __builtin_amdgcn_global_load_lds(
      (const __attribute__((address_space(1))) u32*)(xbase + row*16384 + c4*4),
      (__attribute__((address_space(3))) u32*)(&x_lds[0][0] + k*1024 + w*256),
      16, 0, 0);
  }
  // cooperative coalesced vw stage (16 KB, L2-resident across blocks)
  #pragma unroll
  for (int k = 0; k < 4; k++){
    int i4 = k*256 + tid;            // float4 slot 0..1023
    f32x4 v = *(const f32x4*)(vw + i4*4);
    *(f32x4*)(&vw_lds[i4*4]) = v;
  }
  __syncthreads();

  const float* wsel = (w == 0) ? qw : (w == 1) ? (qw + 64) : (w == 2) ? kw : (kw + 64);
  float bias = (w == 0) ? qb[0] : (w == 1) ? qb[1] : (w == 2) ? kb[0] : kb[1];
  float qkv_ = bias;
  for (int ci = 0; ci < 64; ci++) qkv_ = fmaf(wsel[ci], x_lds[ci][m], qkv_);
  float scale = (w < 2) ? LOG2E : 1.0f;
  qk[combo*16384 + w*4096 + mt*64 + m] = qkv_ * scale;
  if (w >= 2){
    float av = fabsf(qkv_);
    #pragma unroll
    for (int s = 1; s < 64; s <<= 1) av = fmaxf(av, __shfl_xor(av, s, 64));
    if (m == 0) atomicMax(&mk[combo*2 + (w - 2)], __float_as_uint(av));
  }

  float acc[16];
  #pragma unroll
  for (int k = 0; k < 16; k++) acc[k] = vb[w*16 + k];
  for (int ci = 0; ci < 64; ci++){
    float xv = x_lds[ci][m];
    const float* wr = vw_lds + ci;
    #pragma unroll
    for (int k = 0; k < 16; k++)
      acc[k] = fmaf(wr[(w*16 + k)*64], xv, acc[k]);
  }
  __hip_bfloat16* vtc = vt + combo*64*4096 + mt*64 + m;
  #pragma unroll
  for (int k = 0; k < 16; k++)
    vtc[(w*16 + k)*4096] = __float2bfloat16(acc[k]);
}

// ============ half-split flash (R14-proven: K in LDS, cvt_pk, exp2-direct) =
#define EXP2R(x) __builtin_amdgcn_exp2f(x)

#define STAGE(BUFI, MT) do { \
    const __hip_bfloat16* srcb_ = vtc + (MT)*128; \
    _Pragma("unroll") \
    for (int i_ = 0; i_ < 4; i_++){ \
      __builtin_amdgcn_global_load_lds( \
        (const __attribute__((address_space(1))) u32*)(srcb_ + soff[i_]), \
        (__attribute__((address_space(3))) u32*)(&vbuf[BUFI][wave*1024 + i_*4096]), \
        16, 0, 0); \
    } \
    if (wave == 0){ \
      __builtin_amdgcn_global_load_lds( \
        (const __attribute__((address_space(1))) u32*)(qkc + 8192 + (MT)*128 + koff), \
        (__attribute__((address_space(3))) u32*)(&kbuf[BUFI][0]), \
        16, 0, 0); \
    } \
  } while(0)

#define CITER(BUFI, MT, DOSTAGE) do { \
    __syncthreads(); \
    if (DOSTAGE) STAGE(1-(BUFI), (MT)+1); \
    const unsigned char* kp_ = &kbuf[BUFI][0]; \
    _Pragma("unroll") \
    for (int ks_ = 0; ks_ < 4; ks_++){ \
      f32x4 ka = *(const f32x4*)(kp_ + mg32 + ks_*128); \
      f32x4 kb = *(const f32x4*)(kp_ + mg32 + ks_*128 + 16); \
      f32x4 kc = *(const f32x4*)(kp_ + 512 + mg32 + ks_*128); \
      f32x4 kd = *(const f32x4*)(kp_ + 512 + mg32 + ks_*128 + 16); \
      float e0_ = EXP2R(fmaf(q1, ka[0], fmaf(q2, kc[0], nbound))); \
      float e1_ = EXP2R(fmaf(q1, ka[1], fmaf(q2, kc[1], nbound))); \
      float e2_ = EXP2R(fmaf(q1, ka[2], fmaf(q2, kc[2], nbound))); \
      float e3_ = EXP2R(fmaf(q1, ka[3], fmaf(q2, kc[3], nbound))); \
      float f0_ = EXP2R(fmaf(q1, kb[0], fmaf(q2, kd[0], nbound))); \
      float f1_ = EXP2R(fmaf(q1, kb[1], fmaf(q2, kd[1], nbound))); \
      float f2_ = EXP2R(fmaf(q1, kb[2], fmaf(q2, kd[2], nbound))); \
      float f3_ = EXP2R(fmaf(q1, kb[3], fmaf(q2, kd[3], nbound))); \
      den += ((e0_+e1_) + (e2_+e3_)) + ((f0_+f1_) + (f2_+f3_)); \
      union { u32 w[4]; short8 v; } afu_; \
      asm("v_cvt_pk_bf16_f32 %0, %1, %2" : "=v"(afu_.w[0]) : "v"(e0_), "v"(e1_)); \
      asm("v_cvt_pk_bf16_f32 %0, %1, %2" : "=v"(afu_.w[1]) : "v"(e2_), "v"(e3_)); \
      asm("v_cvt_pk_bf16_f32 %0, %1, %2" : "=v"(afu_.w[2]) : "v"(f0_), "v"(f1_)); \
      asm("v_cvt_pk_bf16_f32 %0, %1, %2" : "=v"(afu_.w[3]) : "v"(f2_), "v"(f3_)); \
      short8 af = afu_.v; \
      _Pragma("unroll") \
      for (int cg_ = 0; cg_ < 4; cg_++){ \
        short8 bf = *(const short8*)(&vbuf[BUFI][ra[ks_*4+cg_]]); \
        acc[cg_] = __builtin_amdgcn_mfma_f32_16x16x32_bf16(af, bf, acc[cg_], 0, 0, 0); \
      } \
    } \
  } while(0)

template<int SPLIT>
__global__ __launch_bounds__(256, 4)
void k_flash(const float* __restrict__ x, const float* __restrict__ qk,
             const u32* __restrict__ mk, const __hip_bfloat16* __restrict__ vt,
             const float* __restrict__ g, const float* __restrict__ nl_gamma_p,
             __hip_bfloat16* __restrict__ ctx2b, float* __restrict__ pnum,
             float* __restrict__ pden){
  int combo, ntile, half;
  if (SPLIT){
    combo = blockIdx.x >> 7; int r = blockIdx.x & 127;
    ntile = r >> 1; half = r & 1;
  } else {
    combo = blockIdx.x >> 6; ntile = blockIdx.x & 63; half = 0;
  }
  int b = combo >> 2, si = (combo >> 1) & 1, sj = combo & 1;
  int tid = threadIdx.x; int wave = tid >> 6; int lane = tid & 63;
  int l15 = lane & 15, mg = lane >> 4;

  __shared__ __attribute__((aligned(16))) unsigned char vbuf[2][16384];
  __shared__ __attribute__((aligned(16))) unsigned char kbuf[2][1024];

  const float* qkc = qk + combo*16384;
  int n = ntile*64 + wave*16 + l15;
  float q1 = qkc[n], q2 = qkc[4096 + n];
  float nbound = -(fabsf(q1)*__uint_as_float(mk[combo*2]) +
                   fabsf(q2)*__uint_as_float(mk[combo*2+1]));

  f32x4 acc[4];
  #pragma unroll
  for (int cg = 0; cg < 4; cg++) acc[cg] = (f32x4){0.f,0.f,0.f,0.f};
  float den = 0.f;

  const __hip_bfloat16* vtc = vt + combo*64*4096;

  int ra[16];
  #pragma unroll
  for (int ks = 0; ks < 4; ks++)
    #pragma unroll
    for (int cg = 0; cg < 4; cg++){
      int c = l15 + (cg << 4);
      ra[ks*4+cg] = (c << 8) + ((((ks<<2)+mg) ^ (c & 7)) << 4);
    }
  int soff[4];
  #pragma unroll
  for (int i = 0; i < 4; i++){
    int gi = i*256 + tid;
    int row = gi >> 4, gg = gi & 15;
    int sg = gg ^ (row & 7);
    soff[i] = row*4096 + sg*8;
  }
  int koff = (lane & 31)*4 + (lane >> 5)*4096;
  int mg32 = mg*32;

  const int MT0 = SPLIT ? half*16 : 0;
  const int NP  = SPLIT ? 8 : 16;

  STAGE(0, MT0);
  #pragma unroll 1
  for (int mt2 = 0; mt2 < NP; mt2++){
    CITER(0, MT0 + mt2*2,     1);
    CITER(1, MT0 + mt2*2 + 1, (mt2 < NP-1));
  }

  den += __shfl_xor(den, 16, 64);
  den += __shfl_xor(den, 32, 64);

  if (SPLIT){
    int tile = (half*8 + combo)*64 + ntile;
    #pragma unroll
    for (int cg = 0; cg < 4; cg++){
      int c = l15 + (cg << 4);
      float* pn = pnum + tile*4096 + c*64 + wave*16 + mg*4;
      *(f32x4*)pn = acc[cg];
    }
    if (mg == 0) pden[tile*64 + wave*16 + l15] = den;
  } else {
    float inv = 1.f / den;
    float invj[4];
    #pragma unroll
    for (int j = 0; j < 4; j++) invj[j] = __shfl(inv, mg*4 + j, 64);

    float nlg = nl_gamma_p[0];
    int Y  = si*64 + ntile;
    int X0 = sj*64 + wave*16 + mg*4;
    float fy = Y * (1.f/127.f);
    #pragma unroll
    for (int cg = 0; cg < 4; cg++){
      int c = l15 + (cg << 4);
      f32x4 gv = *(const f32x4*)(g + (b*64 + c)*4);
      float top_l = gv[0] + fy*(gv[2] - gv[0]);
      float top_r = gv[1] + fy*(gv[3] - gv[1]);
      const float* xrow = x + ((b*64 + c)*128 + Y)*128 + X0;
      f32x4 xv = *(const f32x4*)xrow;
      f32x4 o;
      #pragma unroll
      for (int j = 0; j < 4; j++){
        float val = acc[cg][j] * invj[j];
        float ctx = fmaf(nlg, val, xv[j]);
        float fx = (X0 + j) * (1.f/127.f);
        float gg = top_l + fx*(top_r - top_l);
        float gate = 1.f / (1.f + __expf(-gg));
        o[j] = ctx * gate;
      }
      u32 pk0, pk1;
      asm("v_cvt_pk_bf16_f32 %0, %1, %2" : "=v"(pk0) : "v"(o[0]), "v"(o[1]));
      asm("v_cvt_pk_bf16_f32 %0, %1, %2" : "=v"(pk1) : "v"(o[2]), "v"(o[3]));
      u32* dst = (u32*)(ctx2b + (b*64 + c)*16384 + Y*128 + X0);
      dst[0] = pk0; dst[1] = pk1;
    }
  }
}

// ---------------- 4b. combine halves + normalize + gate (bf16 out) --------
template<int S>
__global__ __launch_bounds__(256)
void k_combine(const float* __restrict__ pnum, const float* __restrict__ pden,
               const float* __restrict__ x, const float* __restrict__ g,
               const float* __restrict__ nl_gamma_p, __hip_bfloat16* __restrict__ ctx2b){
  int bid = blockIdx.x; int combo = bid >> 6; int nt = bid & 63;
  int b = combo >> 2, si = (combo >> 1) & 1, sj = combo & 1;
  int tid = threadIdx.x; int c = tid >> 2; int nq = tid & 3;
  int tile0 = combo*64 + nt;
  float inv[16];
  #pragma unroll
  for (int q = 0; q < 4; q++){
    f32x4 dsum = (f32x4){0.f,0.f,0.f,0.f};
    #pragma unroll
    for (int p = 0; p < S; p++){
      f32x4 d = *(const f32x4*)(pden + (tile0 + p*512)*64 + nq*16 + q*4);
      #pragma unroll
      for (int j = 0; j < 4; j++) dsum[j] += d[j];
    }
    #pragma unroll
    for (int j = 0; j < 4; j++) inv[q*4+j] = 1.f / fmaxf(dsum[j], 1e-30f);
  }
  int Y = si*64 + nt; int X0 = sj*64 + nq*16;
  float fy = Y * (1.f/127.f);
  f32x4 gv = *(const f32x4*)(g + (b*64 + c)*4);
  float top_l = gv[0] + fy*(gv[2] - gv[0]);
  float top_r = gv[1] + fy*(gv[3] - gv[1]);
  float nlg = nl_gamma_p[0];
  const float* xrow = x + ((b*64 + c)*128 + Y)*128 + X0;
  __hip_bfloat16* orow = ctx2b + ((b*64 + c)*128 + Y)*128 + X0;
  #pragma unroll
  for (int q = 0; q < 4; q++){
    f32x4 xv = *(const f32x4*)(xrow + q*4);
    f32x4 nsum = (f32x4){0.f,0.f,0.f,0.f};
    #pragma unroll
    for (int p = 0; p < S; p++){
      f32x4 nv = *(const f32x4*)(pnum + (size_t)(tile0 + p*512)*4096 + c*64 + nq*16 + q*4);
      #pragma unroll
      for (int j = 0; j < 4; j++) nsum[j] += nv[j];
    }
    f32x4 o;
    #pragma unroll
    for (int j = 0; j < 4; j++){
      float val = nsum[j] * inv[q*4 + j];
      float ctx = fmaf(nlg, val, xv[j]);
      float fx = (X0 + q*4 + j) * (1.f/127.f);
      float gg = top_l + fx*(top_r - top_l);
      o[j] = ctx / (1.f + __expf(-gg));
    }
    u32 pk0, pk1;
    asm("v_cvt_pk_bf16_f32 %0, %1, %2" : "=v"(pk0) : "v"(o[0]), "v"(o[1]));
    asm("v_cvt_pk_bf16_f32 %0, %1, %2" : "=v"(pk1) : "v"(o[2]), "v"(o[3]));
    u32* dst = (u32*)(orow + q*4);
    dst[0] = pk0; dst[1] = pk1;
  }
}

// ---------------- 5. MFMA 3x3 conv (9 shifted 1x1 GEMMs) + BN + relu ------
__global__ __launch_bounds__(256, 2)
void k_conv(const __hip_bfloat16* __restrict__ ctx2b,
            const __hip_bfloat16* __restrict__ wtb,
            const float* __restrict__ cb, const float* __restrict__ bnw,
            const float* __restrict__ bnb, const float* __restrict__ bnm,
            const float* __restrict__ bnv, const float* __restrict__ gp,
            const float* __restrict__ x, float* __restrict__ out){
  int xh = blockIdx.x & 1; int y = (blockIdx.x >> 1) & 127; int b = blockIdx.x >> 8;
  int xbase = xh*64;
  int tid = threadIdx.x; int w = tid >> 6; int lane = tid & 63;
  int l15 = lane & 15, mg = lane >> 4;

  __shared__ __attribute__((aligned(16))) unsigned char ldsT[25344]; // [3][66][64ci] bf16

  for (int t = tid; t < 1584; t += 256){      // 3*66*8 granules
    int r = t / 528; int rem = t - r*528; int q = rem >> 3; int gg = rem & 7;
    int gy = y + r - 1; int gx = xbase + q - 1;
    short8 val = (short8){0,0,0,0,0,0,0,0};
    if (gy >= 0 && gy < 128 && gx >= 0 && gx < 128){
      const short* src = (const short*)(ctx2b + (b*64 + gg*8)*16384 + gy*128 + gx);
      #pragma unroll
      for (int i = 0; i < 8; i++) val[i] = src[i*16384];
    }
    int gs = gg ^ (q & 7);
    *(short8*)(&ldsT[(r*66 + q)*128 + gs*16]) = val;
  }
  __syncthreads();

  f32x4 acc[4];
  #pragma unroll
  for (int p = 0; p < 4; p++) acc[p] = (f32x4){0.f,0.f,0.f,0.f};

  const short* wv = (const short*)wtb + (w*16 + l15)*64 + mg*8;
  #pragma unroll
  for (int tap = 0; tap < 9; tap++){
    const int r3 = tap / 3, dx = tap % 3;
    #pragma unroll
    for (int h = 0; h < 2; h++){
      short8 af = *(const short8*)(wv + tap*4096 + h*32);
      #pragma unroll
      for (int p = 0; p < 4; p++){
        int q = p*16 + l15 + dx;
        int gs = ((h << 2) + mg) ^ (q & 7);
        short8 bf = *(const short8*)(&ldsT[(r3*66 + q)*128 + gs*16]);
        acc[p] = __builtin_amdgcn_mfma_f32_16x16x32_bf16(af, bf, acc[p], 0, 0, 0);
      }
    }
  }

  float gam = gp[0];
  #pragma unroll
  for (int r = 0; r < 4; r++){
    int co = w*16 + mg*4 + r;
    float scale = bnw[co] * rsqrtf(bnv[co] + 1e-5f);
    float shift = bnb[co] - bnm[co]*scale;
    float cbv = cb[co];
    const float* xrow = x + (b*64 + co)*16384 + y*128 + xbase;
    float* orow = out + (b*64 + co)*16384 + y*128 + xbase;
    #pragma unroll
    for (int p = 0; p < 4; p++){
      int px = p*16 + l15;
      float t = (acc[p][r] + cbv)*scale + shift;
      orow[px] = fmaxf(fmaf(gam, t, xrow[px]), 0.f);
    }
  }
}

extern "C" void kernel_launch(void* const* d_in, const int* in_sizes, int n_in,
                              void* d_out, int out_size, void* d_ws, size_t ws_size,
                              hipStream_t stream) {
  const float* x        = (const float*)d_in[0];
  const float* nl_q_w   = (const float*)d_in[1];
  const float* nl_q_b   = (const float*)d_in[2];
  const float* nl_k_w   = (const float*)d_in[3];
  const float* nl_k_b   = (const float*)d_in[4];
  const float* nl_v_w   = (const float*)d_in[5];
  const float* nl_v_b   = (const float*)d_in[6];
  const float* nl_gamma = (const float*)d_in[7];
  const float* gq_w     = (const float*)d_in[8];
  const float* gq_b     = (const float*)d_in[9];
  const float* gk_w     = (const float*)d_in[10];
  const float* gk_b     = (const float*)d_in[11];
  const float* gv_w     = (const float*)d_in[12];
  const float* gv_b     = (const float*)d_in[13];
  const float* g_gamma  = (const float*)d_in[14];
  const float* conv_w   = (const float*)d_in[15];
  const float* conv_b   = (const float*)d_in[16];
  const float* bn_w     = (const float*)d_in[17];
  const float* bn_b     = (const float*)d_in[18];
  const float* bn_mean  = (const float*)d_in[19];
  const float* bn_var   = (const float*)d_in[20];
  const float* gamma    = (const float*)d_in[21];
  float* out = (float*)d_out;

  float* ws = (float*)d_ws;
  float* pool = ws + WS_POOL;
  float* g    = ws + WS_G;
  float* qk   = ws + WS_QK;
  u32*   mk   = (u32*)(ws + WS_MK);
  __hip_bfloat16* vt   = (__hip_bfloat16*)(ws + WS_VT);
  __hip_bfloat16* wtb  = (__hip_bfloat16*)(ws + WS_WT);
  __hip_bfloat16* ctx2b= (__hip_bfloat16*)(ws + WS_CTX);
  float* pden = ws + WS_PDEN;
  float* pnum = ws + WS_PNUM2;

  k_pool<<<512, 256, 0, stream>>>(x, pool, mk);
  k_gca_wt<<<146, 256, 0, stream>>>(pool, gq_w, gq_b, gk_w, gk_b, gv_w, gv_b,
                                    g_gamma, g, conv_w, wtb);
  k_qkv<<<512, 256, 0, stream>>>(x, nl_q_w, nl_q_b, nl_k_w, nl_k_b,
                                 nl_v_w, nl_v_b, qk, vt, mk);
  if (ws_size >= WS_SPLIT2_BYTES){
    k_flash<1><<<1024, 256, 0, stream>>>(x, qk, mk, vt, g, nl_gamma, ctx2b, pnum, pden);
    k_combine<2><<<512, 256, 0, stream>>>(pnum, pden, x, g, nl_gamma, ctx2b);
  } else {
    k_flash<0><<<512, 256, 0, stream>>>(x, qk, mk, vt, g, nl_gamma, ctx2b, pnum, pden);
  }
  k_conv<<<512, 256, 0, stream>>>(ctx2b, wtb, conv_b, bn_w, bn_b, bn_mean,
                                  bn_var, gamma, x, out);
}

// Round 23
// 99.205 us; speedup vs baseline: 1.5064x; 1.0058x over previous
//
#include <hip/hip_runtime.h>
#include <hip/hip_bf16.h>

typedef float f32x4 __attribute__((ext_vector_type(4)));
typedef short short8 __attribute__((ext_vector_type(8)));
typedef unsigned int u32;

#define LOG2E 1.44269504088896f

// ---------------- ws layout (float offsets) ----------------
#define WS_POOL 0
#define WS_G    1024
#define WS_QK   2048
#define WS_MK   133120
#define WS_VT   134144
#define WS_WT   1182720            // bf16 [tap][co][ci] 36864 elems
#define WS_CTX  1219584            // bf16 [b][c][y][x] 2097152 elems
#define WS_PDEN 3316736            // f32 [1024 tiles][64]
#define WS_PNUM2 3382272           // f32 [1024 tiles][4096]
#define WS_SPLIT2_BYTES ((size_t)(WS_PNUM2 + 4194304) * 4)

// ---------------- 1. adaptive max pool 128x128 -> 2x2 (+ mk zero-init) ----
__global__ void k_pool(const float* __restrict__ x, float* __restrict__ pool,
                       u32* __restrict__ mk){
  if (blockIdx.x == 0 && threadIdx.x < 16) mk[threadIdx.x] = 0u;
  int bid = blockIdx.x;            // ((b*64+c)*4 + t)
  int t4 = bid & 3; int c = (bid >> 2) & 63; int b = bid >> 8;
  int i = t4 >> 1, j = t4 & 1;
  const float* base = x + (((b*64 + c)*128) + i*64)*128 + j*64;
  int tid = threadIdx.x;
  float m = -3.402823466e38f;
  for (int k = tid; k < 4096; k += 256){
    int r = k >> 6, cc = k & 63;
    m = fmaxf(m, base[r*128 + cc]);
  }
  __shared__ float red[256];
  red[tid] = m; __syncthreads();
  for (int s = 128; s > 0; s >>= 1){
    if (tid < s) red[tid] = fmaxf(red[tid], red[tid + s]);
    __syncthreads();
  }
  if (tid == 0) pool[bid] = red[0];
}

// ---------------- 2. tiny non-local on pooled 2x2  +  conv-weight transform
__global__ void k_gca_wt(const float* __restrict__ pool,
                      const float* qw, const float* qb,
                      const float* kw, const float* kb,
                      const float* vw, const float* vb,
                      const float* gamma, float* __restrict__ g,
                      const float* __restrict__ w, __hip_bfloat16* __restrict__ wtb){
  if (blockIdx.x >= 2){
    int idx = (int)(blockIdx.x - 2)*256 + threadIdx.x;   // 36864 total
    if (idx < 36864){
      int ci = idx & 63; int t2 = idx >> 6; int co = t2 & 63; int tap = t2 >> 6;
      wtb[idx] = __float2bfloat16(w[(co*64 + ci)*9 + tap]);
    }
    return;
  }
  int b = blockIdx.x; int c = threadIdx.x;
  __shared__ float P[64][4];
  if (c < 64){
    #pragma unroll
    for (int t = 0; t < 4; t++) P[c][t] = pool[(b*64 + c)*4 + t];
  }
  __syncthreads();
  if (c >= 64) return;
  float q[2][4], kk[2][4];
  #pragma unroll
  for (int i = 0; i < 2; i++)
    #pragma unroll
    for (int n = 0; n < 4; n++){
      float a = qb[i], e = kb[i];
      for (int ci = 0; ci < 64; ci++){
        a += qw[i*64 + ci] * P[ci][n];
        e += kw[i*64 + ci] * P[ci][n];
      }
      q[i][n] = a; kk[i][n] = e;
    }
  float att[4][4];
  #pragma unroll
  for (int n = 0; n < 4; n++){
    float mx = -3.402823466e38f;
    #pragma unroll
    for (int m2 = 0; m2 < 4; m2++){
      att[n][m2] = q[0][n]*kk[0][m2] + q[1][n]*kk[1][m2];
      mx = fmaxf(mx, att[n][m2]);
    }
    float s = 0.f;
    #pragma unroll
    for (int m2 = 0; m2 < 4; m2++){ att[n][m2] = __expf(att[n][m2] - mx); s += att[n][m2]; }
    float inv = 1.f / s;
    #pragma unroll
    for (int m2 = 0; m2 < 4; m2++) att[n][m2] *= inv;
  }
  float v[4];
  #pragma unroll
  for (int m2 = 0; m2 < 4; m2++){
    float a = vb[c];
    for (int ci = 0; ci < 64; ci++) a += vw[c*64 + ci] * P[ci][m2];
    v[m2] = a;
  }
  float gm = gamma[0];
  #pragma unroll
  for (int n = 0; n < 4; n++){
    float o = 0.f;
    #pragma unroll
    for (int m2 = 0; m2 < 4; m2++) o += v[m2] * att[n][m2];
    g[(b*64 + c)*4 + n] = gm*o + P[c][n];
  }
}

// ---------------- 3. q,k,V producer: channel-half split (grid 1024) -------
// bid = combo*128 + mt*2 + h. Block computes V channels h*32..h*32+31
// (wave w: 8 channels h*32+w*8..+7); h==0 blocks also do q,k,mk.
__global__ __launch_bounds__(256, 8)
void k_qkv(const float* __restrict__ x,
           const float* __restrict__ qw, const float* __restrict__ qb,
           const float* __restrict__ kw, const float* __restrict__ kb,
           const float* __restrict__ vw, const float* __restrict__ vb,
           float* __restrict__ qk, __hip_bfloat16* __restrict__ vt,
           u32* __restrict__ mk){
  int h = blockIdx.x & 1; int mt = (blockIdx.x >> 1) & 63; int combo = blockIdx.x >> 7;
  int b = combo >> 2; int si = (combo >> 1) & 1; int sj = combo & 1;
  int tid = threadIdx.x; int w = tid >> 6; int m = tid & 63;

  __shared__ __attribute__((aligned(16))) float x_lds[64][64];
  __shared__ __attribute__((aligned(16))) float vw_lds[2048];   // [32co_local][64ci]

  // async DMA staging of x tile (R21/R22-proven layout)
  const float* xbase = x + (b*64)*16384 + (si*64 + mt)*128 + sj*64;
  #pragma unroll
  for (int k = 0; k < 4; k++){
    int idx = k*256 + tid;
    int row = idx >> 4, c4 = idx & 15;
    __builtin_amdgcn_global_load_lds(
      (const __attribute__((address_space(1))) u32*)(xbase + row*16384 + c4*4),
      (__attribute__((address_space(3))) u32*)(&x_lds[0][0] + k*1024 + w*256),
      16, 0, 0);
  }
  // cooperative coalesced vw half-stage (8 KB, L2-resident across blocks)
  const float* vwh = vw + h*2048;
  #pragma unroll
  for (int k = 0; k < 2; k++){
    int i4 = k*256 + tid;            // float4 slot 0..511
    f32x4 v = *(const f32x4*)(vwh + i4*4);
    *(f32x4*)(&vw_lds[i4*4]) = v;
  }
  __syncthreads();

  if (h == 0){
    const float* wsel = (w == 0) ? qw : (w == 1) ? (qw + 64) : (w == 2) ? kw : (kw + 64);
    float bias = (w == 0) ? qb[0] : (w == 1) ? qb[1] : (w == 2) ? kb[0] : kb[1];
    float qkv_ = bias;
    for (int ci = 0; ci < 64; ci++) qkv_ = fmaf(wsel[ci], x_lds[ci][m], qkv_);
    float scale = (w < 2) ? LOG2E : 1.0f;
    qk[combo*16384 + w*4096 + mt*64 + m] = qkv_ * scale;
    if (w >= 2){
      float av = fabsf(qkv_);
      #pragma unroll
      for (int s = 1; s < 64; s <<= 1) av = fmaxf(av, __shfl_xor(av, s, 64));
      if (m == 0) atomicMax(&mk[combo*2 + (w - 2)], __float_as_uint(av));
    }
  }

  float acc[8];
  #pragma unroll
  for (int k = 0; k < 8; k++) acc[k] = vb[h*32 + w*8 + k];
  for (int ci = 0; ci < 64; ci++){
    float xv = x_lds[ci][m];
    const float* wr = vw_lds + ci;
    #pragma unroll
    for (int k = 0; k < 8; k++)
      acc[k] = fmaf(wr[(w*8 + k)*64], xv, acc[k]);
  }
  __hip_bfloat16* vtc = vt + combo*64*4096 + mt*64 + m;
  #pragma unroll
  for (int k = 0; k < 8; k++)
    vtc[(h*32 + w*8 + k)*4096] = __float2bfloat16(acc[k]);
}

// ============ half-split flash (R14-proven: K in LDS, cvt_pk, exp2-direct) =
#define EXP2R(x) __builtin_amdgcn_exp2f(x)

#define STAGE(BUFI, MT) do { \
    const __hip_bfloat16* srcb_ = vtc + (MT)*128; \
    _Pragma("unroll") \
    for (int i_ = 0; i_ < 4; i_++){ \
      __builtin_amdgcn_global_load_lds( \
        (const __attribute__((address_space(1))) u32*)(srcb_ + soff[i_]), \
        (__attribute__((address_space(3))) u32*)(&vbuf[BUFI][wave*1024 + i_*4096]), \
        16, 0, 0); \
    } \
    if (wave == 0){ \
      __builtin_amdgcn_global_load_lds( \
        (const __attribute__((address_space(1))) u32*)(qkc + 8192 + (MT)*128 + koff), \
        (__attribute__((address_space(3))) u32*)(&kbuf[BUFI][0]), \
        16, 0, 0); \
    } \
  } while(0)

#define CITER(BUFI, MT, DOSTAGE) do { \
    __syncthreads(); \
    if (DOSTAGE) STAGE(1-(BUFI), (MT)+1); \
    const unsigned char* kp_ = &kbuf[BUFI][0]; \
    _Pragma("unroll") \
    for (int ks_ = 0; ks_ < 4; ks_++){ \
      f32x4 ka = *(const f32x4*)(kp_ + mg32 + ks_*128); \
      f32x4 kb = *(const f32x4*)(kp_ + mg32 + ks_*128 + 16); \
      f32x4 kc = *(const f32x4*)(kp_ + 512 + mg32 + ks_*128); \
      f32x4 kd = *(const f32x4*)(kp_ + 512 + mg32 + ks_*128 + 16); \
      float e0_ = EXP2R(fmaf(q1, ka[0], fmaf(q2, kc[0], nbound))); \
      float e1_ = EXP2R(fmaf(q1, ka[1], fmaf(q2, kc[1], nbound))); \
      float e2_ = EXP2R(fmaf(q1, ka[2], fmaf(q2, kc[2], nbound))); \
      float e3_ = EXP2R(fmaf(q1, ka[3], fmaf(q2, kc[3], nbound))); \
      float f0_ = EXP2R(fmaf(q1, kb[0], fmaf(q2, kd[0], nbound))); \
      float f1_ = EXP2R(fmaf(q1, kb[1], fmaf(q2, kd[1], nbound))); \
      float f2_ = EXP2R(fmaf(q1, kb[2], fmaf(q2, kd[2], nbound))); \
      float f3_ = EXP2R(fmaf(q1, kb[3], fmaf(q2, kd[3], nbound))); \
      den += ((e0_+e1_) + (e2_+e3_)) + ((f0_+f1_) + (f2_+f3_)); \
      union { u32 w[4]; short8 v; } afu_; \
      asm("v_cvt_pk_bf16_f32 %0, %1, %2" : "=v"(afu_.w[0]) : "v"(e0_), "v"(e1_)); \
      asm("v_cvt_pk_bf16_f32 %0, %1, %2" : "=v"(afu_.w[1]) : "v"(e2_), "v"(e3_)); \
      asm("v_cvt_pk_bf16_f32 %0, %1, %2" : "=v"(afu_.w[2]) : "v"(f0_), "v"(f1_)); \
      asm("v_cvt_pk_bf16_f32 %0, %1, %2" : "=v"(afu_.w[3]) : "v"(f2_), "v"(f3_)); \
      short8 af = afu_.v; \
      _Pragma("unroll") \
      for (int cg_ = 0; cg_ < 4; cg_++){ \
        short8 bf = *(const short8*)(&vbuf[BUFI][ra[ks_*4+cg_]]); \
        acc[cg_] = __builtin_amdgcn_mfma_f32_16x16x32_bf16(af, bf, acc[cg_], 0, 0, 0); \
      } \
    } \
  } while(0)

template<int SPLIT>
__global__ __launch_bounds__(256, 4)
void k_flash(const float* __restrict__ x, const float* __restrict__ qk,
             const u32* __restrict__ mk, const __hip_bfloat16* __restrict__ vt,
             const float* __restrict__ g, const float* __restrict__ nl_gamma_p,
             __hip_bfloat16* __restrict__ ctx2b, float* __restrict__ pnum,
             float* __restrict__ pden){
  int combo, ntile, half;
  if (SPLIT){
    combo = blockIdx.x >> 7; int r = blockIdx.x & 127;
    ntile = r >> 1; half = r & 1;
  } else {
    combo = blockIdx.x >> 6; ntile = blockIdx.x & 63; half = 0;
  }
  int b = combo >> 2, si = (combo >> 1) & 1, sj = combo & 1;
  int tid = threadIdx.x; int wave = tid >> 6; int lane = tid & 63;
  int l15 = lane & 15, mg = lane >> 4;

  __shared__ __attribute__((aligned(16))) unsigned char vbuf[2][16384];
  __shared__ __attribute__((aligned(16))) unsigned char kbuf[2][1024];

  const float* qkc = qk + combo*16384;
  int n = ntile*64 + wave*16 + l15;
  float q1 = qkc[n], q2 = qkc[4096 + n];
  float nbound = -(fabsf(q1)*__uint_as_float(mk[combo*2]) +
                   fabsf(q2)*__uint_as_float(mk[combo*2+1]));

  f32x4 acc[4];
  #pragma unroll
  for (int cg = 0; cg < 4; cg++) acc[cg] = (f32x4){0.f,0.f,0.f,0.f};
  float den = 0.f;

  const __hip_bfloat16* vtc = vt + combo*64*4096;

  int ra[16];
  #pragma unroll
  for (int ks = 0; ks < 4; ks++)
    #pragma unroll
    for (int cg = 0; cg < 4; cg++){
      int c = l15 + (cg << 4);
      ra[ks*4+cg] = (c << 8) + ((((ks<<2)+mg) ^ (c & 7)) << 4);
    }
  int soff[4];
  #pragma unroll
  for (int i = 0; i < 4; i++){
    int gi = i*256 + tid;
    int row = gi >> 4, gg = gi & 15;
    int sg = gg ^ (row & 7);
    soff[i] = row*4096 + sg*8;
  }
  int koff = (lane & 31)*4 + (lane >> 5)*4096;
  int mg32 = mg*32;

  const int MT0 = SPLIT ? half*16 : 0;
  const int NP  = SPLIT ? 8 : 16;

  STAGE(0, MT0);
  #pragma unroll 1
  for (int mt2 = 0; mt2 < NP; mt2++){
    CITER(0, MT0 + mt2*2,     1);
    CITER(1, MT0 + mt2*2 + 1, (mt2 < NP-1));
  }

  den += __shfl_xor(den, 16, 64);
  den += __shfl_xor(den, 32, 64);

  if (SPLIT){
    int tile = (half*8 + combo)*64 + ntile;
    #pragma unroll
    for (int cg = 0; cg < 4; cg++){
      int c = l15 + (cg << 4);
      float* pn = pnum + tile*4096 + c*64 + wave*16 + mg*4;
      *(f32x4*)pn = acc[cg];
    }
    if (mg == 0) pden[tile*64 + wave*16 + l15] = den;
  } else {
    float inv = 1.f / den;
    float invj[4];
    #pragma unroll
    for (int j = 0; j < 4; j++) invj[j] = __shfl(inv, mg*4 + j, 64);

    float nlg = nl_gamma_p[0];
    int Y  = si*64 + ntile;
    int X0 = sj*64 + wave*16 + mg*4;
    float fy = Y * (1.f/127.f);
    #pragma unroll
    for (int cg = 0; cg < 4; cg++){
      int c = l15 + (cg << 4);
      f32x4 gv = *(const f32x4*)(g + (b*64 + c)*4);
      float top_l = gv[0] + fy*(gv[2] - gv[0]);
      float top_r = gv[1] + fy*(gv[3] - gv[1]);
      const float* xrow = x + ((b*64 + c)*128 + Y)*128 + X0;
      f32x4 xv = *(const f32x4*)xrow;
      f32x4 o;
      #pragma unroll
      for (int j = 0; j < 4; j++){
        float val = acc[cg][j] * invj[j];
        float ctx = fmaf(nlg, val, xv[j]);
        float fx = (X0 + j) * (1.f/127.f);
        float gg = top_l + fx*(top_r - top_l);
        float gate = 1.f / (1.f + __expf(-gg));
        o[j] = ctx * gate;
      }
      u32 pk0, pk1;
      asm("v_cvt_pk_bf16_f32 %0, %1, %2" : "=v"(pk0) : "v"(o[0]), "v"(o[1]));
      asm("v_cvt_pk_bf16_f32 %0, %1, %2" : "=v"(pk1) : "v"(o[2]), "v"(o[3]));
      u32* dst = (u32*)(ctx2b + (b*64 + c)*16384 + Y*128 + X0);
      dst[0] = pk0; dst[1] = pk1;
    }
  }
}

// ---------------- 4b. combine halves + normalize + gate (bf16 out) --------
template<int S>
__global__ __launch_bounds__(256)
void k_combine(const float* __restrict__ pnum, const float* __restrict__ pden,
               const float* __restrict__ x, const float* __restrict__ g,
               const float* __restrict__ nl_gamma_p, __hip_bfloat16* __restrict__ ctx2b){
  int bid = blockIdx.x; int combo = bid >> 6; int nt = bid & 63;
  int b = combo >> 2, si = (combo >> 1) & 1, sj = combo & 1;
  int tid = threadIdx.x; int c = tid >> 2; int nq = tid & 3;
  int tile0 = combo*64 + nt;
  float inv[16];
  #pragma unroll
  for (int q = 0; q < 4; q++){
    f32x4 dsum = (f32x4){0.f,0.f,0.f,0.f};
    #pragma unroll
    for (int p = 0; p < S; p++){
      f32x4 d = *(const f32x4*)(pden + (tile0 + p*512)*64 + nq*16 + q*4);
      #pragma unroll
      for (int j = 0; j < 4; j++) dsum[j] += d[j];
    }
    #pragma unroll
    for (int j = 0; j < 4; j++) inv[q*4+j] = 1.f / fmaxf(dsum[j], 1e-30f);
  }
  int Y = si*64 + nt; int X0 = sj*64 + nq*16;
  float fy = Y * (1.f/127.f);
  f32x4 gv = *(const f32x4*)(g + (b*64 + c)*4);
  float top_l = gv[0] + fy*(gv[2] - gv[0]);
  float top_r = gv[1] + fy*(gv[3] - gv[1]);
  float nlg = nl_gamma_p[0];
  const float* xrow = x + ((b*64 + c)*128 + Y)*128 + X0;
  __hip_bfloat16* orow = ctx2b + ((b*64 + c)*128 + Y)*128 + X0;
  #pragma unroll
  for (int q = 0; q < 4; q++){
    f32x4 xv = *(const f32x4*)(xrow + q*4);
    f32x4 nsum = (f32x4){0.f,0.f,0.f,0.f};
    #pragma unroll
    for (int p = 0; p < S; p++){
      f32x4 nv = *(const f32x4*)(pnum + (size_t)(tile0 + p*512)*4096 + c*64 + nq*16 + q*4);
      #pragma unroll
      for (int j = 0; j < 4; j++) nsum[j] += nv[j];
    }
    f32x4 o;
    #pragma unroll
    for (int j = 0; j < 4; j++){
      float val = nsum[j] * inv[q*4 + j];
      float ctx = fmaf(nlg, val, xv[j]);
      float fx = (X0 + q*4 + j) * (1.f/127.f);
      float gg = top_l + fx*(top_r - top_l);
      o[j] = ctx / (1.f + __expf(-gg));
    }
    u32 pk0, pk1;
    asm("v_cvt_pk_bf16_f32 %0, %1, %2" : "=v"(pk0) : "v"(o[0]), "v"(o[1]));
    asm("v_cvt_pk_bf16_f32 %0, %1, %2" : "=v"(pk1) : "v"(o[2]), "v"(o[3]));
    u32* dst = (u32*)(orow + q*4);
    dst[0] = pk0; dst[1] = pk1;
  }
}

// ---------------- 5. MFMA 3x3 conv (9 shifted 1x1 GEMMs) + BN + relu ------
__global__ __launch_bounds__(256, 2)
void k_conv(const __hip_bfloat16* __restrict__ ctx2b,
            const __hip_bfloat16* __restrict__ wtb,
            const float* __restrict__ cb, const float* __restrict__ bnw,
            const float* __restrict__ bnb, const float* __restrict__ bnm,
            const float* __restrict__ bnv, const float* __restrict__ gp,
            const float* __restrict__ x, float* __restrict__ out){
  int xh = blockIdx.x & 1; int y = (blockIdx.x >> 1) & 127; int b = blockIdx.x >> 8;
  int xbase = xh*64;
  int tid = threadIdx.x; int w = tid >> 6; int lane = tid & 63;
  int l15 = lane & 15, mg = lane >> 4;

  __shared__ __attribute__((aligned(16))) unsigned char ldsT[25344]; // [3][66][64ci] bf16

  for (int t = tid; t < 1584; t += 256){      // 3*66*8 granules
    int r = t / 528; int rem = t - r*528; int q = rem >> 3; int gg = rem & 7;
    int gy = y + r - 1; int gx = xbase + q - 1;
    short8 val = (short8){0,0,0,0,0,0,0,0};
    if (gy >= 0 && gy < 128 && gx >= 0 && gx < 128){
      const short* src = (const short*)(ctx2b + (b*64 + gg*8)*16384 + gy*128 + gx);
      #pragma unroll
      for (int i = 0; i < 8; i++) val[i] = src[i*16384];
    }
    int gs = gg ^ (q & 7);
    *(short8*)(&ldsT[(r*66 + q)*128 + gs*16]) = val;
  }
  __syncthreads();

  f32x4 acc[4];
  #pragma unroll
  for (int p = 0; p < 4; p++) acc[p] = (f32x4){0.f,0.f,0.f,0.f};

  const short* wv = (const short*)wtb + (w*16 + l15)*64 + mg*8;
  #pragma unroll
  for (int tap = 0; tap < 9; tap++){
    const int r3 = tap / 3, dx = tap % 3;
    #pragma unroll
    for (int h = 0; h < 2; h++){
      short8 af = *(const short8*)(wv + tap*4096 + h*32);
      #pragma unroll
      for (int p = 0; p < 4; p++){
        int q = p*16 + l15 + dx;
        int gs = ((h << 2) + mg) ^ (q & 7);
        short8 bf = *(const short8*)(&ldsT[(r3*66 + q)*128 + gs*16]);
        acc[p] = __builtin_amdgcn_mfma_f32_16x16x32_bf16(af, bf, acc[p], 0, 0, 0);
      }
    }
  }

  float gam = gp[0];
  #pragma unroll
  for (int r = 0; r < 4; r++){
    int co = w*16 + mg*4 + r;
    float scale = bnw[co] * rsqrtf(bnv[co] + 1e-5f);
    float shift = bnb[co] - bnm[co]*scale;
    float cbv = cb[co];
    const float* xrow = x + (b*64 + co)*16384 + y*128 + xbase;
    float* orow = out + (b*64 + co)*16384 + y*128 + xbase;
    #pragma unroll
    for (int p = 0; p < 4; p++){
      int px = p*16 + l15;
      float t = (acc[p][r] + cbv)*scale + shift;
      orow[px] = fmaxf(fmaf(gam, t, xrow[px]), 0.f);
    }
  }
}

extern "C" void kernel_launch(void* const* d_in, const int* in_sizes, int n_in,
                              void* d_out, int out_size, void* d_ws, size_t ws_size,
                              hipStream_t stream) {
  const float* x        = (const float*)d_in[0];
  const float* nl_q_w   = (const float*)d_in[1];
  const float* nl_q_b   = (const float*)d_in[2];
  const float* nl_k_w   = (const float*)d_in[3];
  const float* nl_k_b   = (const float*)d_in[4];
  const float* nl_v_w   = (const float*)d_in[5];
  const float* nl_v_b   = (const float*)d_in[6];
  const float* nl_gamma = (const float*)d_in[7];
  const float* gq_w     = (const float*)d_in[8];
  const float* gq_b     = (const float*)d_in[9];
  const float* gk_w     = (const float*)d_in[10];
  const float* gk_b     = (const float*)d_in[11];
  const float* gv_w     = (const float*)d_in[12];
  const float* gv_b     = (const float*)d_in[13];
  const float* g_gamma  = (const float*)d_in[14];
  const float* conv_w   = (const float*)d_in[15];
  const float* conv_b   = (const float*)d_in[16];
  const float* bn_w     = (const float*)d_in[17];
  const float* bn_b     = (const float*)d_in[18];
  const float* bn_mean  = (const float*)d_in[19];
  const float* bn_var   = (const float*)d_in[20];
  const float* gamma    = (const float*)d_in[21];
  float* out = (float*)d_out;

  float* ws = (float*)d_ws;
  float* pool = ws + WS_POOL;
  float* g    = ws + WS_G;
  float* qk   = ws + WS_QK;
  u32*   mk   = (u32*)(ws + WS_MK);
  __hip_bfloat16* vt   = (__hip_bfloat16*)(ws + WS_VT);
  __hip_bfloat16* wtb  = (__hip_bfloat16*)(ws + WS_WT);
  __hip_bfloat16* ctx2b= (__hip_bfloat16*)(ws + WS_CTX);
  float* pden = ws + WS_PDEN;
  float* pnum = ws + WS_PNUM2;

  k_pool<<<512, 256, 0, stream>>>(x, pool, mk);
  k_gca_wt<<<146, 256, 0, stream>>>(pool, gq_w, gq_b, gk_w, gk_b, gv_w, gv_b,
                                    g_gamma, g, conv_w, wtb);
  k_qkv<<<1024, 256, 0, stream>>>(x, nl_q_w, nl_q_b, nl_k_w, nl_k_b,
                                  nl_v_w, nl_v_b, qk, vt, mk);
  if (ws_size >= WS_SPLIT2_BYTES){
    k_flash<1><<<1024, 256, 0, stream>>>(x, qk, mk, vt, g, nl_gamma, ctx2b, pnum, pden);
    k_combine<2><<<512, 256, 0, stream>>>(pnum, pden, x, g, nl_gamma, ctx2b);
  } else {
    k_flash<0><<<512, 256, 0, stream>>>(x, qk, mk, vt, g, nl_gamma, ctx2b, pnum, pden);
  }
  k_conv<<<512, 256, 0, stream>>>(ctx2b, wtb, conv_b, bn_w, bn_b, bn_mean,
                                  bn_var, gamma, x, out);
}

// Round 24
// 98.782 us; speedup vs baseline: 1.5129x; 1.0043x over previous
//
#include <hip/hip_runtime.h>
#include <hip/hip_bf16.h>

typedef float f32x4 __attribute__((ext_vector_type(4)));
typedef short short8 __attribute__((ext_vector_type(8)));
typedef unsigned int u32;

#define LOG2E 1.44269504088896f

// ---------------- ws layout (float offsets) ----------------
#define WS_POOL 0
#define WS_G    1024
#define WS_QK   2048
#define WS_MK   133120
#define WS_VT   134144
#define WS_WT   1182720            // bf16 [tap][co][ci] 36864 elems
#define WS_CTX  1219584            // bf16 [b][c][y][x] 2097152 elems
#define WS_PDEN 3316736            // f32 [1024 tiles][64]
#define WS_PNUM2 3382272           // f32 [1024 tiles][4096]
#define WS_SPLIT2_BYTES ((size_t)(WS_PNUM2 + 4194304) * 4)

// ---------------- 1. adaptive max pool 128x128 -> 2x2 (+ mk zero-init) ----
__global__ void k_pool(const float* __restrict__ x, float* __restrict__ pool,
                       u32* __restrict__ mk){
  if (blockIdx.x == 0 && threadIdx.x < 16) mk[threadIdx.x] = 0u;
  int bid = blockIdx.x;            // ((b*64+c)*4 + t)
  int t4 = bid & 3; int c = (bid >> 2) & 63; int b = bid >> 8;
  int i = t4 >> 1, j = t4 & 1;
  const float* base = x + (((b*64 + c)*128) + i*64)*128 + j*64;
  int tid = threadIdx.x;
  float m = -3.402823466e38f;
  for (int k = tid; k < 4096; k += 256){
    int r = k >> 6, cc = k & 63;
    m = fmaxf(m, base[r*128 + cc]);
  }
  __shared__ float red[256];
  red[tid] = m; __syncthreads();
  for (int s = 128; s > 0; s >>= 1){
    if (tid < s) red[tid] = fmaxf(red[tid], red[tid + s]);
    __syncthreads();
  }
  if (tid == 0) pool[bid] = red[0];
}

// ---------------- 2. tiny non-local on pooled 2x2  +  conv-weight transform
__global__ void k_gca_wt(const float* __restrict__ pool,
                      const float* qw, const float* qb,
                      const float* kw, const float* kb,
                      const float* vw, const float* vb,
                      const float* gamma, float* __restrict__ g,
                      const float* __restrict__ w, __hip_bfloat16* __restrict__ wtb){
  if (blockIdx.x >= 2){
    int idx = (int)(blockIdx.x - 2)*256 + threadIdx.x;   // 36864 total
    if (idx < 36864){
      int ci = idx & 63; int t2 = idx >> 6; int co = t2 & 63; int tap = t2 >> 6;
      wtb[idx] = __float2bfloat16(w[(co*64 + ci)*9 + tap]);
    }
    return;
  }
  int b = blockIdx.x; int c = threadIdx.x;
  __shared__ float P[64][4];
  if (c < 64){
    #pragma unroll
    for (int t = 0; t < 4; t++) P[c][t] = pool[(b*64 + c)*4 + t];
  }
  __syncthreads();
  if (c >= 64) return;
  float q[2][4], kk[2][4];
  #pragma unroll
  for (int i = 0; i < 2; i++)
    #pragma unroll
    for (int n = 0; n < 4; n++){
      float a = qb[i], e = kb[i];
      for (int ci = 0; ci < 64; ci++){
        a += qw[i*64 + ci] * P[ci][n];
        e += kw[i*64 + ci] * P[ci][n];
      }
      q[i][n] = a; kk[i][n] = e;
    }
  float att[4][4];
  #pragma unroll
  for (int n = 0; n < 4; n++){
    float mx = -3.402823466e38f;
    #pragma unroll
    for (int m2 = 0; m2 < 4; m2++){
      att[n][m2] = q[0][n]*kk[0][m2] + q[1][n]*kk[1][m2];
      mx = fmaxf(mx, att[n][m2]);
    }
    float s = 0.f;
    #pragma unroll
    for (int m2 = 0; m2 < 4; m2++){ att[n][m2] = __expf(att[n][m2] - mx); s += att[n][m2]; }
    float inv = 1.f / s;
    #pragma unroll
    for (int m2 = 0; m2 < 4; m2++) att[n][m2] *= inv;
  }
  float v[4];
  #pragma unroll
  for (int m2 = 0; m2 < 4; m2++){
    float a = vb[c];
    for (int ci = 0; ci < 64; ci++) a += vw[c*64 + ci] * P[ci][m2];
    v[m2] = a;
  }
  float gm = gamma[0];
  #pragma unroll
  for (int n = 0; n < 4; n++){
    float o = 0.f;
    #pragma unroll
    for (int m2 = 0; m2 < 4; m2++) o += v[m2] * att[n][m2];
    g[(b*64 + c)*4 + n] = gm*o + P[c][n];
  }
}

// ---------------- 3. q,k,V producer: channel-half split (grid 1024) -------
__global__ __launch_bounds__(256, 8)
void k_qkv(const float* __restrict__ x,
           const float* __restrict__ qw, const float* __restrict__ qb,
           const float* __restrict__ kw, const float* __restrict__ kb,
           const float* __restrict__ vw, const float* __restrict__ vb,
           float* __restrict__ qk, __hip_bfloat16* __restrict__ vt,
           u32* __restrict__ mk){
  int h = blockIdx.x & 1; int mt = (blockIdx.x >> 1) & 63; int combo = blockIdx.x >> 7;
  int b = combo >> 2; int si = (combo >> 1) & 1; int sj = combo & 1;
  int tid = threadIdx.x; int w = tid >> 6; int m = tid & 63;

  __shared__ __attribute__((aligned(16))) float x_lds[64][64];
  __shared__ __attribute__((aligned(16))) float vw_lds[2048];   // [32co_local][64ci]

  const float* xbase = x + (b*64)*16384 + (si*64 + mt)*128 + sj*64;
  #pragma unroll
  for (int k = 0; k < 4; k++){
    int idx = k*256 + tid;
    int row = idx >> 4, c4 = idx & 15;
    __builtin_amdgcn_global_load_lds(
      (const __attribute__((address_space(1))) u32*)(xbase + row*16384 + c4*4),
      (__attribute__((address_space(3))) u32*)(&x_lds[0][0] + k*1024 + w*256),
      16, 0, 0);
  }
  const float* vwh = vw + h*2048;
  #pragma unroll
  for (int k = 0; k < 2; k++){
    int i4 = k*256 + tid;
    f32x4 v = *(const f32x4*)(vwh + i4*4);
    *(f32x4*)(&vw_lds[i4*4]) = v;
  }
  __syncthreads();

  if (h == 0){
    const float* wsel = (w == 0) ? qw : (w == 1) ? (qw + 64) : (w == 2) ? kw : (kw + 64);
    float bias = (w == 0) ? qb[0] : (w == 1) ? qb[1] : (w == 2) ? kb[0] : kb[1];
    float qkv_ = bias;
    for (int ci = 0; ci < 64; ci++) qkv_ = fmaf(wsel[ci], x_lds[ci][m], qkv_);
    float scale = (w < 2) ? LOG2E : 1.0f;
    qk[combo*16384 + w*4096 + mt*64 + m] = qkv_ * scale;
    if (w >= 2){
      float av = fabsf(qkv_);
      #pragma unroll
      for (int s = 1; s < 64; s <<= 1) av = fmaxf(av, __shfl_xor(av, s, 64));
      if (m == 0) atomicMax(&mk[combo*2 + (w - 2)], __float_as_uint(av));
    }
  }

  float acc[8];
  #pragma unroll
  for (int k = 0; k < 8; k++) acc[k] = vb[h*32 + w*8 + k];
  for (int ci = 0; ci < 64; ci++){
    float xv = x_lds[ci][m];
    const float* wr = vw_lds + ci;
    #pragma unroll
    for (int k = 0; k < 8; k++)
      acc[k] = fmaf(wr[(w*8 + k)*64], xv, acc[k]);
  }
  __hip_bfloat16* vtc = vt + combo*64*4096 + mt*64 + m;
  #pragma unroll
  for (int k = 0; k < 8; k++)
    vtc[(h*32 + w*8 + k)*4096] = __float2bfloat16(acc[k]);
}

// ============ half-split flash (R14-proven: K in LDS, cvt_pk, exp2-direct) =
#define EXP2R(x) __builtin_amdgcn_exp2f(x)

#define STAGE(BUFI, MT) do { \
    const __hip_bfloat16* srcb_ = vtc + (MT)*128; \
    _Pragma("unroll") \
    for (int i_ = 0; i_ < 4; i_++){ \
      __builtin_amdgcn_global_load_lds( \
        (const __attribute__((address_space(1))) u32*)(srcb_ + soff[i_]), \
        (__attribute__((address_space(3))) u32*)(&vbuf[BUFI][wave*1024 + i_*4096]), \
        16, 0, 0); \
    } \
    if (wave == 0){ \
      __builtin_amdgcn_global_load_lds( \
        (const __attribute__((address_space(1))) u32*)(qkc + 8192 + (MT)*128 + koff), \
        (__attribute__((address_space(3))) u32*)(&kbuf[BUFI][0]), \
        16, 0, 0); \
    } \
  } while(0)

#define CITER(BUFI, MT, DOSTAGE) do { \
    __syncthreads(); \
    if (DOSTAGE) STAGE(1-(BUFI), (MT)+1); \
    const unsigned char* kp_ = &kbuf[BUFI][0]; \
    _Pragma("unroll") \
    for (int ks_ = 0; ks_ < 4; ks_++){ \
      f32x4 ka = *(const f32x4*)(kp_ + mg32 + ks_*128); \
      f32x4 kb = *(const f32x4*)(kp_ + mg32 + ks_*128 + 16); \
      f32x4 kc = *(const f32x4*)(kp_ + 512 + mg32 + ks_*128); \
      f32x4 kd = *(const f32x4*)(kp_ + 512 + mg32 + ks_*128 + 16); \
      float e0_ = EXP2R(fmaf(q1, ka[0], fmaf(q2, kc[0], nbound))); \
      float e1_ = EXP2R(fmaf(q1, ka[1], fmaf(q2, kc[1], nbound))); \
      float e2_ = EXP2R(fmaf(q1, ka[2], fmaf(q2, kc[2], nbound))); \
      float e3_ = EXP2R(fmaf(q1, ka[3], fmaf(q2, kc[3], nbound))); \
      float f0_ = EXP2R(fmaf(q1, kb[0], fmaf(q2, kd[0], nbound))); \
      float f1_ = EXP2R(fmaf(q1, kb[1], fmaf(q2, kd[1], nbound))); \
      float f2_ = EXP2R(fmaf(q1, kb[2], fmaf(q2, kd[2], nbound))); \
      float f3_ = EXP2R(fmaf(q1, kb[3], fmaf(q2, kd[3], nbound))); \
      den += ((e0_+e1_) + (e2_+e3_)) + ((f0_+f1_) + (f2_+f3_)); \
      union { u32 w[4]; short8 v; } afu_; \
      asm("v_cvt_pk_bf16_f32 %0, %1, %2" : "=v"(afu_.w[0]) : "v"(e0_), "v"(e1_)); \
      asm("v_cvt_pk_bf16_f32 %0, %1, %2" : "=v"(afu_.w[1]) : "v"(e2_), "v"(e3_)); \
      asm("v_cvt_pk_bf16_f32 %0, %1, %2" : "=v"(afu_.w[2]) : "v"(f0_), "v"(f1_)); \
      asm("v_cvt_pk_bf16_f32 %0, %1, %2" : "=v"(afu_.w[3]) : "v"(f2_), "v"(f3_)); \
      short8 af = afu_.v; \
      _Pragma("unroll") \
      for (int cg_ = 0; cg_ < 4; cg_++){ \
        short8 bf = *(const short8*)(&vbuf[BUFI][ra[ks_*4+cg_]]); \
        acc[cg_] = __builtin_amdgcn_mfma_f32_16x16x32_bf16(af, bf, acc[cg_], 0, 0, 0); \
      } \
    } \
  } while(0)

template<int SPLIT>
__global__ __launch_bounds__(256, 4)
void k_flash(const float* __restrict__ x, const float* __restrict__ qk,
             const u32* __restrict__ mk, const __hip_bfloat16* __restrict__ vt,
             const float* __restrict__ g, const float* __restrict__ nl_gamma_p,
             __hip_bfloat16* __restrict__ ctx2b, float* __restrict__ pnum,
             float* __restrict__ pden){
  int combo, ntile, half;
  if (SPLIT){
    combo = blockIdx.x >> 7; int r = blockIdx.x & 127;
    ntile = r >> 1; half = r & 1;
  } else {
    combo = blockIdx.x >> 6; ntile = blockIdx.x & 63; half = 0;
  }
  int b = combo >> 2, si = (combo >> 1) & 1, sj = combo & 1;
  int tid = threadIdx.x; int wave = tid >> 6; int lane = tid & 63;
  int l15 = lane & 15, mg = lane >> 4;

  __shared__ __attribute__((aligned(16))) unsigned char vbuf[2][16384];
  __shared__ __attribute__((aligned(16))) unsigned char kbuf[2][1024];

  const float* qkc = qk + combo*16384;
  int n = ntile*64 + wave*16 + l15;
  float q1 = qkc[n], q2 = qkc[4096 + n];
  float nbound = -(fabsf(q1)*__uint_as_float(mk[combo*2]) +
                   fabsf(q2)*__uint_as_float(mk[combo*2+1]));

  f32x4 acc[4];
  #pragma unroll
  for (int cg = 0; cg < 4; cg++) acc[cg] = (f32x4){0.f,0.f,0.f,0.f};
  float den = 0.f;

  const __hip_bfloat16* vtc = vt + combo*64*4096;

  int ra[16];
  #pragma unroll
  for (int ks = 0; ks < 4; ks++)
    #pragma unroll
    for (int cg = 0; cg < 4; cg++){
      int c = l15 + (cg << 4);
      ra[ks*4+cg] = (c << 8) + ((((ks<<2)+mg) ^ (c & 7)) << 4);
    }
  int soff[4];
  #pragma unroll
  for (int i = 0; i < 4; i++){
    int gi = i*256 + tid;
    int row = gi >> 4, gg = gi & 15;
    int sg = gg ^ (row & 7);
    soff[i] = row*4096 + sg*8;
  }
  int koff = (lane & 31)*4 + (lane >> 5)*4096;
  int mg32 = mg*32;

  const int MT0 = SPLIT ? half*16 : 0;
  const int NP  = SPLIT ? 8 : 16;

  STAGE(0, MT0);
  #pragma unroll 1
  for (int mt2 = 0; mt2 < NP; mt2++){
    CITER(0, MT0 + mt2*2,     1);
    CITER(1, MT0 + mt2*2 + 1, (mt2 < NP-1));
  }

  den += __shfl_xor(den, 16, 64);
  den += __shfl_xor(den, 32, 64);

  if (SPLIT){
    int tile = (half*8 + combo)*64 + ntile;
    #pragma unroll
    for (int cg = 0; cg < 4; cg++){
      int c = l15 + (cg << 4);
      float* pn = pnum + tile*4096 + c*64 + wave*16 + mg*4;
      *(f32x4*)pn = acc[cg];
    }
    if (mg == 0) pden[tile*64 + wave*16 + l15] = den;
  } else {
    float inv = 1.f / den;
    float invj[4];
    #pragma unroll
    for (int j = 0; j < 4; j++) invj[j] = __shfl(inv, mg*4 + j, 64);

    float nlg = nl_gamma_p[0];
    int Y  = si*64 + ntile;
    int X0 = sj*64 + wave*16 + mg*4;
    float fy = Y * (1.f/127.f);
    #pragma unroll
    for (int cg = 0; cg < 4; cg++){
      int c = l15 + (cg << 4);
      f32x4 gv = *(const f32x4*)(g + (b*64 + c)*4);
      float top_l = gv[0] + fy*(gv[2] - gv[0]);
      float top_r = gv[1] + fy*(gv[3] - gv[1]);
      const float* xrow = x + ((b*64 + c)*128 + Y)*128 + X0;
      f32x4 xv = *(const f32x4*)xrow;
      f32x4 o;
      #pragma unroll
      for (int j = 0; j < 4; j++){
        float val = acc[cg][j] * invj[j];
        float ctx = fmaf(nlg, val, xv[j]);
        float fx = (X0 + j) * (1.f/127.f);
        float gg = top_l + fx*(top_r - top_l);
        float gate = 1.f / (1.f + __expf(-gg));
        o[j] = ctx * gate;
      }
      u32 pk0, pk1;
      asm("v_cvt_pk_bf16_f32 %0, %1, %2" : "=v"(pk0) : "v"(o[0]), "v"(o[1]));
      asm("v_cvt_pk_bf16_f32 %0, %1, %2" : "=v"(pk1) : "v"(o[2]), "v"(o[3]));
      u32* dst = (u32*)(ctx2b + (b*64 + c)*16384 + Y*128 + X0);
      dst[0] = pk0; dst[1] = pk1;
    }
  }
}

// ---------------- 4b. combine halves + normalize + gate (bf16 out) --------
template<int S>
__global__ __launch_bounds__(256)
void k_combine(const float* __restrict__ pnum, const float* __restrict__ pden,
               const float* __restrict__ x, const float* __restrict__ g,
               const float* __restrict__ nl_gamma_p, __hip_bfloat16* __restrict__ ctx2b){
  int bid = blockIdx.x; int combo = bid >> 6; int nt = bid & 63;
  int b = combo >> 2, si = (combo >> 1) & 1, sj = combo & 1;
  int tid = threadIdx.x; int c = tid >> 2; int nq = tid & 3;
  int tile0 = combo*64 + nt;
  float inv[16];
  #pragma unroll
  for (int q = 0; q < 4; q++){
    f32x4 dsum = (f32x4){0.f,0.f,0.f,0.f};
    #pragma unroll
    for (int p = 0; p < S; p++){
      f32x4 d = *(const f32x4*)(pden + (tile0 + p*512)*64 + nq*16 + q*4);
      #pragma unroll
      for (int j = 0; j < 4; j++) dsum[j] += d[j];
    }
    #pragma unroll
    for (int j = 0; j < 4; j++) inv[q*4+j] = 1.f / fmaxf(dsum[j], 1e-30f);
  }
  int Y = si*64 + nt; int X0 = sj*64 + nq*16;
  float fy = Y * (1.f/127.f);
  f32x4 gv = *(const f32x4*)(g + (b*64 + c)*4);
  float top_l = gv[0] + fy*(gv[2] - gv[0]);
  float top_r = gv[1] + fy*(gv[3] - gv[1]);
  float nlg = nl_gamma_p[0];
  const float* xrow = x + ((b*64 + c)*128 + Y)*128 + X0;
  __hip_bfloat16* orow = ctx2b + ((b*64 + c)*128 + Y)*128 + X0;
  #pragma unroll
  for (int q = 0; q < 4; q++){
    f32x4 xv = *(const f32x4*)(xrow + q*4);
    f32x4 nsum = (f32x4){0.f,0.f,0.f,0.f};
    #pragma unroll
    for (int p = 0; p < S; p++){
      f32x4 nv = *(const f32x4*)(pnum + (size_t)(tile0 + p*512)*4096 + c*64 + nq*16 + q*4);
      #pragma unroll
      for (int j = 0; j < 4; j++) nsum[j] += nv[j];
    }
    f32x4 o;
    #pragma unroll
    for (int j = 0; j < 4; j++){
      float val = nsum[j] * inv[q*4 + j];
      float ctx = fmaf(nlg, val, xv[j]);
      float fx = (X0 + q*4 + j) * (1.f/127.f);
      float gg = top_l + fx*(top_r - top_l);
      o[j] = ctx / (1.f + __expf(-gg));
    }
    u32 pk0, pk1;
    asm("v_cvt_pk_bf16_f32 %0, %1, %2" : "=v"(pk0) : "v"(o[0]), "v"(o[1]));
    asm("v_cvt_pk_bf16_f32 %0, %1, %2" : "=v"(pk1) : "v"(o[2]), "v"(o[3]));
    u32* dst = (u32*)(orow + q*4);
    dst[0] = pk0; dst[1] = pk1;
  }
}

// ---------------- 5. MFMA 3x3 conv (9 shifted 1x1 GEMMs) + BN + relu ------
__global__ __launch_bounds__(256, 2)
void k_conv(const __hip_bfloat16* __restrict__ ctx2b,
            const __hip_bfloat16* __restrict__ wtb,
            const float* __restrict__ cb, const float* __restrict__ bnw,
            const float* __restrict__ bnb, const float* __restrict__ bnm,
            const float* __restrict__ bnv, const float* __restrict__ gp,
            const float* __restrict__ x, float* __restrict__ out){
  int xh = blockIdx.x & 1; int y = (blockIdx.x >> 1) & 127; int b = blockIdx.x >> 8;
  int xbase = xh*64;
  int tid = threadIdx.x; int w = tid >> 6; int lane = tid & 63;
  int l15 = lane & 15, mg = lane >> 4;

  __shared__ __attribute__((aligned(16))) unsigned char ldsT[25344]; // [3][66][64ci] bf16

  for (int t = tid; t < 1584; t += 256){      // 3*66*8 granules
    int r = t / 528; int rem = t - r*528; int q = rem >> 3; int gg = rem & 7;
    int gy = y + r - 1; int gx = xbase + q - 1;
    short8 val = (short8){0,0,0,0,0,0,0,0};
    if (gy >= 0 && gy < 128 && gx >= 0 && gx < 128){
      const short* src = (const short*)(ctx2b + (b*64 + gg*8)*16384 + gy*128 + gx);
      #pragma unroll
      for (int i = 0; i < 8; i++) val[i] = src[i*16384];
    }
    int gs = gg ^ (q & 7);
    *(short8*)(&ldsT[(r*66 + q)*128 + gs*16]) = val;
  }
  __syncthreads();

  f32x4 acc[4];
  #pragma unroll
  for (int p = 0; p < 4; p++) acc[p] = (f32x4){0.f,0.f,0.f,0.f};

  const short* wv = (const short*)wtb + (w*16 + l15)*64 + mg*8;
  #pragma unroll
  for (int tap = 0; tap < 9; tap++){
    const int r3 = tap / 3, dx = tap % 3;
    #pragma unroll
    for (int h = 0; h < 2; h++){
      short8 af = *(const short8*)(wv + tap*4096 + h*32);
      #pragma unroll
      for (int p = 0; p < 4; p++){
        int q = p*16 + l15 + dx;
        int gs = ((h << 2) + mg) ^ (q & 7);
        short8 bf = *(const short8*)(&ldsT[(r3*66 + q)*128 + gs*16]);
        acc[p] = __builtin_amdgcn_mfma_f32_16x16x32_bf16(af, bf, acc[p], 0, 0, 0);
      }
    }
  }

  float gam = gp[0];
  #pragma unroll
  for (int r = 0; r < 4; r++){
    int co = w*16 + mg*4 + r;
    float scale = bnw[co] * rsqrtf(bnv[co] + 1e-5f);
    float shift = bnb[co] - bnm[co]*scale;
    float cbv = cb[co];
    const float* xrow = x + (b*64 + co)*16384 + y*128 + xbase;
    float* orow = out + (b*64 + co)*16384 + y*128 + xbase;
    #pragma unroll
    for (int p = 0; p < 4; p++){
      int px = p*16 + l15;
      float t = (acc[p][r] + cbv)*scale + shift;
      orow[px] = fmaxf(fmaf(gam, t, xrow[px]), 0.f);
    }
  }
}

extern "C" void kernel_launch(void* const* d_in, const int* in_sizes, int n_in,
                              void* d_out, int out_size, void* d_ws, size_t ws_size,
                              hipStream_t stream) {
  const float* x        = (const float*)d_in[0];
  const float* nl_q_w   = (const float*)d_in[1];
  const float* nl_q_b   = (const float*)d_in[2];
  const float* nl_k_w   = (const float*)d_in[3];
  const float* nl_k_b   = (const float*)d_in[4];
  const float* nl_v_w   = (const float*)d_in[5];
  const float* nl_v_b   = (const float*)d_in[6];
  const float* nl_gamma = (const float*)d_in[7];
  const float* gq_w     = (const float*)d_in[8];
  const float* gq_b     = (const float*)d_in[9];
  const float* gk_w     = (const float*)d_in[10];
  const float* gk_b     = (const float*)d_in[11];
  const float* gv_w     = (const float*)d_in[12];
  const float* gv_b     = (const float*)d_in[13];
  const float* g_gamma  = (const float*)d_in[14];
  const float* conv_w   = (const float*)d_in[15];
  const float* conv_b   = (const float*)d_in[16];
  const float* bn_w     = (const float*)d_in[17];
  const float* bn_b     = (const float*)d_in[18];
  const float* bn_mean  = (const float*)d_in[19];
  const float* bn_var   = (const float*)d_in[20];
  const float* gamma    = (const float*)d_in[21];
  float* out = (float*)d_out;

  float* ws = (float*)d_ws;
  float* pool = ws + WS_POOL;
  float* g    = ws + WS_G;
  float* qk   = ws + WS_QK;
  u32*   mk   = (u32*)(ws + WS_MK);
  __hip_bfloat16* vt   = (__hip_bfloat16*)(ws + WS_VT);
  __hip_bfloat16* wtb  = (__hip_bfloat16*)(ws + WS_WT);
  __hip_bfloat16* ctx2b= (__hip_bfloat16*)(ws + WS_CTX);
  float* pden = ws + WS_PDEN;
  float* pnum = ws + WS_PNUM2;

  k_pool<<<512, 256, 0, stream>>>(x, pool, mk);
  k_gca_wt<<<146, 256, 0, stream>>>(pool, gq_w, gq_b, gk_w, gk_b, gv_w, gv_b,
                                    g_gamma, g, conv_w, wtb);
  k_qkv<<<1024, 256, 0, stream>>>(x, nl_q_w, nl_q_b, nl_k_w, nl_k_b,
                                  nl_v_w, nl_v_b, qk, vt, mk);
  if (ws_size >= WS_SPLIT2_BYTES){
    k_flash<1><<<1024, 256, 0, stream>>>(x, qk, mk, vt, g, nl_gamma, ctx2b, pnum, pden);
    k_combine<2><<<512, 256, 0, stream>>>(pnum, pden, x, g, nl_gamma, ctx2b);
  } else {
    k_flash<0><<<512, 256, 0, stream>>>(x, qk, mk, vt, g, nl_gamma, ctx2b, pnum, pden);
  }
  k_conv<<<512, 256, 0, stream>>>(ctx2b, wtb, conv_b, bn_w, bn_b, bn_mean,
                                  bn_var, gamma, x, out);
}